// Round 1
// baseline (728.360 us; speedup 1.0000x reference)
//
#include <hip/hip_runtime.h>
#include <hip/hip_bf16.h>
#include <cstdint>
#include <cstddef>

typedef __attribute__((ext_vector_type(8))) short bf16x8;
typedef __attribute__((ext_vector_type(4))) float f32x4;

#define DEVI __device__ __forceinline__

DEVI unsigned short f2bf(float f) {
  union { float f; unsigned u; } x; x.f = f;
  unsigned r = x.u + 0x7fffu + ((x.u >> 16) & 1u);
  return (unsigned short)(r >> 16);
}

DEVI float exp2fast(float x) {
#if __has_builtin(__builtin_amdgcn_exp2f)
  return __builtin_amdgcn_exp2f(x);
#else
  return exp2f(x);
#endif
}

DEVI void gload_lds16(const void* g, void* l) {
  __builtin_amdgcn_global_load_lds((const __attribute__((address_space(1))) void*)g,
                                   (__attribute__((address_space(3))) void*)l, 16, 0, 0);
}

DEVI f32x4 mfma16(bf16x8 a, bf16x8 b, f32x4 c) {
  return __builtin_amdgcn_mfma_f32_16x16x32_bf16(a, b, c, 0, 0, 0);
}

// ---------------- weight transpose fp32 (K,N) -> bf16 (N,K) ----------------
__global__ __launch_bounds__(256) void transpose_to_bf16(
    const float* __restrict__ w, unsigned short* __restrict__ wt, int K, int N) {
  __shared__ float tile[32][33];
  const int n0 = blockIdx.x * 32, k0 = blockIdx.y * 32;
  const int tx = threadIdx.x, ty = threadIdx.y;
#pragma unroll
  for (int i = 0; i < 4; i++)
    tile[ty + i * 8][tx] = w[(size_t)(k0 + ty + i * 8) * N + n0 + tx];
  __syncthreads();
#pragma unroll
  for (int i = 0; i < 4; i++)
    wt[(size_t)(n0 + ty + i * 8) * K + k0 + tx] = f2bf(tile[tx][ty + i * 8]);
}

// ---------------- bf16 per-head transpose (BH,T,HS) -> (BH,HS,T) ----------------
__global__ __launch_bounds__(256) void transpose_v(
    const unsigned short* __restrict__ in, unsigned short* __restrict__ out) {
  __shared__ unsigned short tile[32][33];
  const int bh = blockIdx.z;
  const unsigned short* inp = in + (size_t)bh * 2048 * 128;
  unsigned short* op = out + (size_t)bh * 2048 * 128;
  const int t0 = blockIdx.x * 32, d0 = blockIdx.y * 32;
  const int tx = threadIdx.x, ty = threadIdx.y;
#pragma unroll
  for (int i = 0; i < 4; i++)
    tile[ty + i * 8][tx] = inp[(size_t)(t0 + ty + i * 8) * 128 + d0 + tx];
  __syncthreads();
#pragma unroll
  for (int i = 0; i < 4; i++)
    op[(size_t)(d0 + ty + i * 8) * 2048 + t0 + tx] = tile[tx][ty + i * 8];
}

// ---------------- LayerNorm: f32 row(2048) -> bf16 ----------------
__global__ __launch_bounds__(256) void ln_kernel(
    const float* __restrict__ x, const float* __restrict__ gw,
    const float* __restrict__ gb, unsigned short* __restrict__ out) {
  __shared__ float red[8];
  const int row = blockIdx.x, tid = threadIdx.x;
  const float* xr = x + (size_t)row * 2048;
  f32x4 a = *((const f32x4*)xr + tid * 2);
  f32x4 b = *((const f32x4*)xr + tid * 2 + 1);
  float s = a[0] + a[1] + a[2] + a[3] + b[0] + b[1] + b[2] + b[3];
#pragma unroll
  for (int m = 32; m >= 1; m >>= 1) s += __shfl_xor(s, m, 64);
  if ((tid & 63) == 0) red[tid >> 6] = s;
  __syncthreads();
  const float mu = (red[0] + red[1] + red[2] + red[3]) * (1.f / 2048.f);
  float d[8]; float ss = 0.f;
#pragma unroll
  for (int j = 0; j < 8; j++) {
    float v = ((j < 4) ? a[j] : b[j - 4]) - mu;
    d[j] = v; ss += v * v;
  }
#pragma unroll
  for (int m = 32; m >= 1; m >>= 1) ss += __shfl_xor(ss, m, 64);
  __syncthreads();
  if ((tid & 63) == 0) red[4 + (tid >> 6)] = ss;
  __syncthreads();
  const float var = (red[4] + red[5] + red[6] + red[7]) * (1.f / 2048.f);
  const float rstd = rsqrtf(var + 1e-5f);
  f32x4 w0 = *((const f32x4*)gw + tid * 2), w1 = *((const f32x4*)gw + tid * 2 + 1);
  f32x4 b0 = *((const f32x4*)gb + tid * 2), b1 = *((const f32x4*)gb + tid * 2 + 1);
  union { bf16x8 v; unsigned short u[8]; } o;
#pragma unroll
  for (int j = 0; j < 8; j++) {
    float wv = (j < 4) ? w0[j] : w1[j - 4];
    float bv = (j < 4) ? b0[j] : b1[j - 4];
    o.u[j] = f2bf(d[j] * rstd * wv + bv);
  }
  *(bf16x8*)(out + (size_t)row * 2048 + tid * 8) = o.v;
}

// =====================================================================
// Shared epilogue: C[row,col] with row = m0+(2jj+wm)*16+g*4+r, col = n0+(4n+wn)*16+i
// EPI 0: QKV scatter to q/k/v head layout bf16; EPI 1: GELU -> bf16; EPI 2: +res -> f32
template <int EPI>
DEVI void epilogue_store(float v, int row, int col, int Nn,
                         const float* __restrict__ res, float* __restrict__ outf,
                         unsigned short* __restrict__ outb, unsigned short* __restrict__ oq,
                         unsigned short* __restrict__ ok, unsigned short* __restrict__ ov) {
  if constexpr (EPI == 0) {
    const int which = col >> 11, cc = col & 2047;
    const int hh = cc >> 7, hs = cc & 127;
    const int bb = row >> 11, tt = row & 2047;
    const size_t bh = (size_t)(bb * 16 + hh);
    const unsigned short bits = f2bf(v);
    if (which == 0) oq[(bh * 2048 + tt) * 128 + hs] = bits;
    else if (which == 1) ok[(bh * 2048 + tt) * 128 + hs] = bits;
    else ov[(bh * 2048 + tt) * 128 + hs] = bits;
  } else if constexpr (EPI == 1) {
    const float ge = 0.5f * v * (1.0f + erff(v * 0.70710678118654752f));
    outb[(size_t)row * Nn + col] = f2bf(ge);
  } else {
    outf[(size_t)row * Nn + col] = v + res[(size_t)row * Nn + col];
  }
}

// sched_group_barrier masks
#define SGB_MFMA 0x008
#define SGB_DSRD 0x100

// ---------------- 256x256 4-phase/K-tile GEMM (used for FC) ----------------
// v2: fragment reads software-pipelined one phase ahead, interleaved into the
// previous phase's MFMA cluster via sched_group_barrier; last K-tile peeled so
// the main loop has no branches. vmcnt schedule is unchanged (it already
// drains exactly the chunk each relocated read needs).
template <int EPI>
__global__ __launch_bounds__(512, 2) void gemm256(
    const unsigned short* __restrict__ A, const unsigned short* __restrict__ Bt,
    const float* __restrict__ bias, const float* __restrict__ res,
    float* __restrict__ outf, unsigned short* __restrict__ outb,
    unsigned short* __restrict__ oq, unsigned short* __restrict__ ok,
    unsigned short* __restrict__ ov, int Nn, int Kk, int nbn) {
  __shared__ unsigned short As[2][256 * 64];
  __shared__ unsigned short Bs[2][256 * 64];
  const int tid = threadIdx.x;
  const int lane = tid & 63, wid = tid >> 6;
  const int i = lane & 15, g = lane >> 4;
  const int wm = wid >> 2, wn = wid & 3;
  const int nwg = gridDim.x;
  const int sid = (blockIdx.x & 7) * (nwg >> 3) + (blockIdx.x >> 3);
  const int m0 = (sid / nbn) * 256, n0 = (sid % nbn) * 256;

  auto stageA = [&](int bf, int kt, int h) {
#pragma unroll
    for (int c = 0; c < 2; c++) {
      const int cb = h * 1024 + c * 512 + wid * 64;
      const int ci = cb + lane;
      const int row = ci >> 3;
      const int kc = (ci & 7) ^ (row & 7);
      gload_lds16(A + (size_t)(m0 + row) * Kk + kt + kc * 8, &As[bf][(size_t)cb * 8]);
    }
  };
  auto stageB = [&](int bf, int kt, int h) {
#pragma unroll
    for (int c = 0; c < 2; c++) {
      const int cb = h * 1024 + c * 512 + wid * 64;
      const int ci = cb + lane;
      const int row = ci >> 3;
      const int kc = (ci & 7) ^ (row & 7);
      gload_lds16(Bt + (size_t)(n0 + row) * Kk + kt + kc * 8, &Bs[bf][(size_t)cb * 8]);
    }
  };
  auto ldA = [&](int bf, int jj, int ks) -> bf16x8 {
    const int row = (2 * jj + wm) * 16 + i;
    return *(const bf16x8*)((const char*)&As[bf][0] + row * 128 + ((((ks << 2) + g) ^ (i & 7)) << 4));
  };
  auto ldB = [&](int bf, int n, int ks) -> bf16x8 {
    const int row = (4 * n + wn) * 16 + i;
    return *(const bf16x8*)((const char*)&Bs[bf][0] + row * 128 + ((((ks << 2) + g) ^ (i & 7)) << 4));
  };

  f32x4 acc[8][4] = {};
  const int NT = Kk >> 6;

  // prologue: stage tile 0 fully, wait h0 halves, preload phase-0 fragments
  stageA(0, 0, 0);
  stageB(0, 0, 0);
  stageB(0, 0, 1);
  stageA(0, 0, 1);
  asm volatile("s_waitcnt vmcnt(4)" ::: "memory");
  __builtin_amdgcn_s_barrier();
  __builtin_amdgcn_sched_barrier(0);

  bf16x8 a_lo[4][2], a_hi[4][2], b_lo[2][2], b_hi[2][2];
#pragma unroll
  for (int jj = 0; jj < 4; jj++) { a_lo[jj][0] = ldA(0, jj, 0); a_lo[jj][1] = ldA(0, jj, 1); }
#pragma unroll
  for (int n = 0; n < 2; n++) { b_lo[n][0] = ldB(0, n, 0); b_lo[n][1] = ldB(0, n, 1); }

  for (int t = 0; t < NT - 1; ++t) {
    const int cur = t & 1, nxt = cur ^ 1;
    const int ktn = (t + 1) << 6;
    // ---- phase 0: MFMA q00 (a_lo x b_lo) + prefetch b_hi(cur)
    stageA(nxt, ktn, 0);
    asm volatile("s_waitcnt vmcnt(4)" ::: "memory");
    __builtin_amdgcn_s_barrier();
    asm volatile("s_waitcnt lgkmcnt(0)" ::: "memory");
    __builtin_amdgcn_sched_barrier(0);
    __builtin_amdgcn_s_setprio(1);
#pragma unroll
    for (int jj = 0; jj < 4; jj++)
#pragma unroll
      for (int n = 0; n < 2; n++) acc[jj][n] = mfma16(a_lo[jj][0], b_lo[n][0], acc[jj][n]);
#pragma unroll
    for (int jj = 0; jj < 4; jj++)
#pragma unroll
      for (int n = 0; n < 2; n++) acc[jj][n] = mfma16(a_lo[jj][1], b_lo[n][1], acc[jj][n]);
#pragma unroll
    for (int n = 0; n < 2; n++) { b_hi[n][0] = ldB(cur, 2 + n, 0); b_hi[n][1] = ldB(cur, 2 + n, 1); }
#pragma unroll
    for (int z = 0; z < 4; z++) {
      __builtin_amdgcn_sched_group_barrier(SGB_MFMA, 4, 0);
      __builtin_amdgcn_sched_group_barrier(SGB_DSRD, 1, 0);
    }
    __builtin_amdgcn_s_setprio(0);
    __builtin_amdgcn_s_barrier();
    __builtin_amdgcn_sched_barrier(0);
    // ---- phase 1: MFMA q01 (a_lo x b_hi) + prefetch a_hi(cur)
    stageB(nxt, ktn, 0);
    asm volatile("s_waitcnt vmcnt(4)" ::: "memory");
    __builtin_amdgcn_s_barrier();
    asm volatile("s_waitcnt lgkmcnt(0)" ::: "memory");
    __builtin_amdgcn_sched_barrier(0);
    __builtin_amdgcn_s_setprio(1);
#pragma unroll
    for (int jj = 0; jj < 4; jj++)
#pragma unroll
      for (int n = 0; n < 2; n++) acc[jj][2 + n] = mfma16(a_lo[jj][0], b_hi[n][0], acc[jj][2 + n]);
#pragma unroll
    for (int jj = 0; jj < 4; jj++)
#pragma unroll
      for (int n = 0; n < 2; n++) acc[jj][2 + n] = mfma16(a_lo[jj][1], b_hi[n][1], acc[jj][2 + n]);
#pragma unroll
    for (int jj = 0; jj < 4; jj++) { a_hi[jj][0] = ldA(cur, 4 + jj, 0); a_hi[jj][1] = ldA(cur, 4 + jj, 1); }
#pragma unroll
    for (int z = 0; z < 8; z++) {
      __builtin_amdgcn_sched_group_barrier(SGB_MFMA, 2, 0);
      __builtin_amdgcn_sched_group_barrier(SGB_DSRD, 1, 0);
    }
    __builtin_amdgcn_s_setprio(0);
    __builtin_amdgcn_s_barrier();
    __builtin_amdgcn_sched_barrier(0);
    // ---- phase 2: MFMA q10 (a_hi x b_lo), no reads
    stageB(nxt, ktn, 1);
    __builtin_amdgcn_s_barrier();
    asm volatile("s_waitcnt lgkmcnt(0)" ::: "memory");
    __builtin_amdgcn_sched_barrier(0);
    __builtin_amdgcn_s_setprio(1);
#pragma unroll
    for (int jj = 0; jj < 4; jj++)
#pragma unroll
      for (int n = 0; n < 2; n++) acc[4 + jj][n] = mfma16(a_hi[jj][0], b_lo[n][0], acc[4 + jj][n]);
#pragma unroll
    for (int jj = 0; jj < 4; jj++)
#pragma unroll
      for (int n = 0; n < 2; n++) acc[4 + jj][n] = mfma16(a_hi[jj][1], b_lo[n][1], acc[4 + jj][n]);
    __builtin_amdgcn_s_setprio(0);
    __builtin_amdgcn_s_barrier();
    __builtin_amdgcn_sched_barrier(0);
    // ---- phase 3: MFMA q11 (a_hi x b_hi) + prefetch a_lo,b_lo of tile t+1 (nxt)
    stageA(nxt, ktn, 1);
    asm volatile("s_waitcnt vmcnt(4)" ::: "memory");
    __builtin_amdgcn_s_barrier();
    asm volatile("s_waitcnt lgkmcnt(0)" ::: "memory");
    __builtin_amdgcn_sched_barrier(0);
    __builtin_amdgcn_s_setprio(1);
#pragma unroll
    for (int jj = 0; jj < 4; jj++)
#pragma unroll
      for (int n = 0; n < 2; n++) acc[4 + jj][2 + n] = mfma16(a_hi[jj][0], b_hi[n][0], acc[4 + jj][2 + n]);
#pragma unroll
    for (int jj = 0; jj < 4; jj++)
#pragma unroll
      for (int n = 0; n < 2; n++) acc[4 + jj][2 + n] = mfma16(a_hi[jj][1], b_hi[n][1], acc[4 + jj][2 + n]);
#pragma unroll
    for (int jj = 0; jj < 4; jj++) { a_lo[jj][0] = ldA(nxt, jj, 0); a_lo[jj][1] = ldA(nxt, jj, 1); }
#pragma unroll
    for (int n = 0; n < 2; n++) { b_lo[n][0] = ldB(nxt, n, 0); b_lo[n][1] = ldB(nxt, n, 1); }
#pragma unroll
    for (int z = 0; z < 4; z++) {
      __builtin_amdgcn_sched_group_barrier(SGB_MFMA, 2, 0);
      __builtin_amdgcn_sched_group_barrier(SGB_DSRD, 2, 0);
    }
#pragma unroll
    for (int z = 0; z < 4; z++) {
      __builtin_amdgcn_sched_group_barrier(SGB_MFMA, 2, 0);
      __builtin_amdgcn_sched_group_barrier(SGB_DSRD, 1, 0);
    }
    __builtin_amdgcn_s_setprio(0);
    __builtin_amdgcn_s_barrier();
    __builtin_amdgcn_sched_barrier(0);
  }

  // ---- peeled tail tile t = NT-1 (no staging, no next-tile prefetch)
  {
    const int cur = (NT - 1) & 1;
    // phase 0
    asm volatile("s_waitcnt vmcnt(2)" ::: "memory");
    __builtin_amdgcn_s_barrier();
    asm volatile("s_waitcnt lgkmcnt(0)" ::: "memory");
    __builtin_amdgcn_sched_barrier(0);
    __builtin_amdgcn_s_setprio(1);
#pragma unroll
    for (int jj = 0; jj < 4; jj++)
#pragma unroll
      for (int n = 0; n < 2; n++) acc[jj][n] = mfma16(a_lo[jj][0], b_lo[n][0], acc[jj][n]);
#pragma unroll
    for (int jj = 0; jj < 4; jj++)
#pragma unroll
      for (int n = 0; n < 2; n++) acc[jj][n] = mfma16(a_lo[jj][1], b_lo[n][1], acc[jj][n]);
#pragma unroll
    for (int n = 0; n < 2; n++) { b_hi[n][0] = ldB(cur, 2 + n, 0); b_hi[n][1] = ldB(cur, 2 + n, 1); }
#pragma unroll
    for (int z = 0; z < 4; z++) {
      __builtin_amdgcn_sched_group_barrier(SGB_MFMA, 4, 0);
      __builtin_amdgcn_sched_group_barrier(SGB_DSRD, 1, 0);
    }
    __builtin_amdgcn_s_setprio(0);
    __builtin_amdgcn_s_barrier();
    __builtin_amdgcn_sched_barrier(0);
    // phase 1
    asm volatile("s_waitcnt vmcnt(0)" ::: "memory");
    __builtin_amdgcn_s_barrier();
    asm volatile("s_waitcnt lgkmcnt(0)" ::: "memory");
    __builtin_amdgcn_sched_barrier(0);
    __builtin_amdgcn_s_setprio(1);
#pragma unroll
    for (int jj = 0; jj < 4; jj++)
#pragma unroll
      for (int n = 0; n < 2; n++) acc[jj][2 + n] = mfma16(a_lo[jj][0], b_hi[n][0], acc[jj][2 + n]);
#pragma unroll
    for (int jj = 0; jj < 4; jj++)
#pragma unroll
      for (int n = 0; n < 2; n++) acc[jj][2 + n] = mfma16(a_lo[jj][1], b_hi[n][1], acc[jj][2 + n]);
#pragma unroll
    for (int jj = 0; jj < 4; jj++) { a_hi[jj][0] = ldA(cur, 4 + jj, 0); a_hi[jj][1] = ldA(cur, 4 + jj, 1); }
#pragma unroll
    for (int z = 0; z < 8; z++) {
      __builtin_amdgcn_sched_group_barrier(SGB_MFMA, 2, 0);
      __builtin_amdgcn_sched_group_barrier(SGB_DSRD, 1, 0);
    }
    __builtin_amdgcn_s_setprio(0);
    __builtin_amdgcn_s_barrier();
    __builtin_amdgcn_sched_barrier(0);
    // phase 2
    __builtin_amdgcn_s_barrier();
    asm volatile("s_waitcnt lgkmcnt(0)" ::: "memory");
    __builtin_amdgcn_sched_barrier(0);
    __builtin_amdgcn_s_setprio(1);
#pragma unroll
    for (int jj = 0; jj < 4; jj++)
#pragma unroll
      for (int n = 0; n < 2; n++) acc[4 + jj][n] = mfma16(a_hi[jj][0], b_lo[n][0], acc[4 + jj][n]);
#pragma unroll
    for (int jj = 0; jj < 4; jj++)
#pragma unroll
      for (int n = 0; n < 2; n++) acc[4 + jj][n] = mfma16(a_hi[jj][1], b_lo[n][1], acc[4 + jj][n]);
    __builtin_amdgcn_s_setprio(0);
    __builtin_amdgcn_s_barrier();
    __builtin_amdgcn_sched_barrier(0);
    // phase 3
    __builtin_amdgcn_s_setprio(1);
#pragma unroll
    for (int jj = 0; jj < 4; jj++)
#pragma unroll
      for (int n = 0; n < 2; n++) acc[4 + jj][2 + n] = mfma16(a_hi[jj][0], b_hi[n][0], acc[4 + jj][2 + n]);
#pragma unroll
    for (int jj = 0; jj < 4; jj++)
#pragma unroll
      for (int n = 0; n < 2; n++) acc[4 + jj][2 + n] = mfma16(a_hi[jj][1], b_hi[n][1], acc[4 + jj][2 + n]);
    __builtin_amdgcn_s_setprio(0);
  }

#pragma unroll
  for (int jj = 0; jj < 8; jj++)
#pragma unroll
    for (int n = 0; n < 4; n++) {
      const int col = n0 + (4 * n + wn) * 16 + i;
      const float bv = bias[col];
#pragma unroll
      for (int r = 0; r < 4; r++) {
        const int row = m0 + (2 * jj + wm) * 16 + g * 4 + r;
        epilogue_store<EPI>(acc[jj][n][r] + bv, row, col, Nn, res, outf, outb, oq, ok, ov);
      }
    }
}

// ---------------- 128x256 2-phase/K-tile GEMM (QKV / proj / FC2) ----------------
// v2: same pipelining treatment; af(t+1)/b_lo(t+1) are prefetched inside the
// p1 MFMA cluster (SSA renaming gives free double-buffering of af).
template <int EPI>
__global__ __launch_bounds__(512, 2) void gemm128(
    const unsigned short* __restrict__ A, const unsigned short* __restrict__ Bt,
    const float* __restrict__ bias, const float* __restrict__ res,
    float* __restrict__ outf, unsigned short* __restrict__ outb,
    unsigned short* __restrict__ oq, unsigned short* __restrict__ ok,
    unsigned short* __restrict__ ov, int Nn, int Kk, int nbn) {
  __shared__ unsigned short As[2][128 * 64];   // 32 KiB
  __shared__ unsigned short Bs[2][256 * 64];   // 64 KiB
  const int tid = threadIdx.x;
  const int lane = tid & 63, wid = tid >> 6;
  const int i = lane & 15, g = lane >> 4;
  const int wm = wid >> 2, wn = wid & 3;
  const int nwg = gridDim.x;
  const int sid = (blockIdx.x & 7) * (nwg >> 3) + (blockIdx.x >> 3);
  const int m0 = (sid / nbn) * 128, n0 = (sid % nbn) * 256;

  auto stageA = [&](int bf, int kt) {
#pragma unroll
    for (int c = 0; c < 2; c++) {
      const int cb = c * 512 + wid * 64;
      const int ci = cb + lane;
      const int row = ci >> 3;
      const int kc = (ci & 7) ^ (row & 7);
      gload_lds16(A + (size_t)(m0 + row) * Kk + kt + kc * 8, &As[bf][(size_t)cb * 8]);
    }
  };
  auto stageB = [&](int bf, int kt, int h) {
#pragma unroll
    for (int c = 0; c < 2; c++) {
      const int cb = h * 1024 + c * 512 + wid * 64;
      const int ci = cb + lane;
      const int row = ci >> 3;
      const int kc = (ci & 7) ^ (row & 7);
      gload_lds16(Bt + (size_t)(n0 + row) * Kk + kt + kc * 8, &Bs[bf][(size_t)cb * 8]);
    }
  };
  auto ldA = [&](int bf, int jj, int ks) -> bf16x8 {
    const int row = (2 * jj + wm) * 16 + i;
    return *(const bf16x8*)((const char*)&As[bf][0] + row * 128 + ((((ks << 2) + g) ^ (i & 7)) << 4));
  };
  auto ldB = [&](int bf, int n, int ks) -> bf16x8 {
    const int row = (4 * n + wn) * 16 + i;
    return *(const bf16x8*)((const char*)&Bs[bf][0] + row * 128 + ((((ks << 2) + g) ^ (i & 7)) << 4));
  };

  f32x4 acc[4][4] = {};
  const int NT = Kk >> 6;

  stageA(0, 0);
  stageB(0, 0, 0);
  stageB(0, 0, 1);
  asm volatile("s_waitcnt vmcnt(2)" ::: "memory");
  __builtin_amdgcn_s_barrier();
  __builtin_amdgcn_sched_barrier(0);

  bf16x8 af[4][2], b_lo[2][2], b_hi[2][2];
#pragma unroll
  for (int jj = 0; jj < 4; jj++) { af[jj][0] = ldA(0, jj, 0); af[jj][1] = ldA(0, jj, 1); }
#pragma unroll
  for (int n = 0; n < 2; n++) { b_lo[n][0] = ldB(0, n, 0); b_lo[n][1] = ldB(0, n, 1); }

  for (int t = 0; t < NT - 1; ++t) {
    const int cur = t & 1, nxt = cur ^ 1;
    const int ktn = (t + 1) << 6;
    // ---- PH0: MFMA (af x b_lo) + prefetch b_hi(cur)
    stageA(nxt, ktn);
    stageB(nxt, ktn, 0);
    stageB(nxt, ktn, 1);
    asm volatile("s_waitcnt vmcnt(6)" ::: "memory");
    __builtin_amdgcn_s_barrier();
    asm volatile("s_waitcnt lgkmcnt(0)" ::: "memory");
    __builtin_amdgcn_sched_barrier(0);
    __builtin_amdgcn_s_setprio(1);
#pragma unroll
    for (int jj = 0; jj < 4; jj++)
#pragma unroll
      for (int n = 0; n < 2; n++) acc[jj][n] = mfma16(af[jj][0], b_lo[n][0], acc[jj][n]);
#pragma unroll
    for (int jj = 0; jj < 4; jj++)
#pragma unroll
      for (int n = 0; n < 2; n++) acc[jj][n] = mfma16(af[jj][1], b_lo[n][1], acc[jj][n]);
#pragma unroll
    for (int n = 0; n < 2; n++) { b_hi[n][0] = ldB(cur, 2 + n, 0); b_hi[n][1] = ldB(cur, 2 + n, 1); }
#pragma unroll
    for (int z = 0; z < 4; z++) {
      __builtin_amdgcn_sched_group_barrier(SGB_MFMA, 4, 0);
      __builtin_amdgcn_sched_group_barrier(SGB_DSRD, 1, 0);
    }
    __builtin_amdgcn_s_setprio(0);
    __builtin_amdgcn_s_barrier();
    __builtin_amdgcn_sched_barrier(0);
    // ---- PH1: MFMA (af x b_hi) + prefetch af,b_lo of tile t+1 (nxt)
    asm volatile("s_waitcnt vmcnt(2)" ::: "memory");
    __builtin_amdgcn_s_barrier();
    asm volatile("s_waitcnt lgkmcnt(0)" ::: "memory");
    __builtin_amdgcn_sched_barrier(0);
    __builtin_amdgcn_s_setprio(1);
#pragma unroll
    for (int jj = 0; jj < 4; jj++)
#pragma unroll
      for (int n = 0; n < 2; n++) acc[jj][2 + n] = mfma16(af[jj][0], b_hi[n][0], acc[jj][2 + n]);
#pragma unroll
    for (int jj = 0; jj < 4; jj++)
#pragma unroll
      for (int n = 0; n < 2; n++) acc[jj][2 + n] = mfma16(af[jj][1], b_hi[n][1], acc[jj][2 + n]);
#pragma unroll
    for (int jj = 0; jj < 4; jj++) { af[jj][0] = ldA(nxt, jj, 0); af[jj][1] = ldA(nxt, jj, 1); }
#pragma unroll
    for (int n = 0; n < 2; n++) { b_lo[n][0] = ldB(nxt, n, 0); b_lo[n][1] = ldB(nxt, n, 1); }
#pragma unroll
    for (int z = 0; z < 4; z++) {
      __builtin_amdgcn_sched_group_barrier(SGB_MFMA, 2, 0);
      __builtin_amdgcn_sched_group_barrier(SGB_DSRD, 2, 0);
    }
#pragma unroll
    for (int z = 0; z < 4; z++) {
      __builtin_amdgcn_sched_group_barrier(SGB_MFMA, 2, 0);
      __builtin_amdgcn_sched_group_barrier(SGB_DSRD, 1, 0);
    }
    __builtin_amdgcn_s_setprio(0);
    __builtin_amdgcn_s_barrier();
    __builtin_amdgcn_sched_barrier(0);
  }

  // ---- peeled tail tile t = NT-1
  {
    const int cur = (NT - 1) & 1;
    // PH0
    asm volatile("s_waitcnt vmcnt(0)" ::: "memory");
    __builtin_amdgcn_s_barrier();
    asm volatile("s_waitcnt lgkmcnt(0)" ::: "memory");
    __builtin_amdgcn_sched_barrier(0);
    __builtin_amdgcn_s_setprio(1);
#pragma unroll
    for (int jj = 0; jj < 4; jj++)
#pragma unroll
      for (int n = 0; n < 2; n++) acc[jj][n] = mfma16(af[jj][0], b_lo[n][0], acc[jj][n]);
#pragma unroll
    for (int jj = 0; jj < 4; jj++)
#pragma unroll
      for (int n = 0; n < 2; n++) acc[jj][n] = mfma16(af[jj][1], b_lo[n][1], acc[jj][n]);
#pragma unroll
    for (int n = 0; n < 2; n++) { b_hi[n][0] = ldB(cur, 2 + n, 0); b_hi[n][1] = ldB(cur, 2 + n, 1); }
#pragma unroll
    for (int z = 0; z < 4; z++) {
      __builtin_amdgcn_sched_group_barrier(SGB_MFMA, 4, 0);
      __builtin_amdgcn_sched_group_barrier(SGB_DSRD, 1, 0);
    }
    __builtin_amdgcn_s_setprio(0);
    __builtin_amdgcn_s_barrier();
    __builtin_amdgcn_sched_barrier(0);
    // PH1
    asm volatile("s_waitcnt lgkmcnt(0)" ::: "memory");
    __builtin_amdgcn_sched_barrier(0);
    __builtin_amdgcn_s_setprio(1);
#pragma unroll
    for (int jj = 0; jj < 4; jj++)
#pragma unroll
      for (int n = 0; n < 2; n++) acc[jj][2 + n] = mfma16(af[jj][0], b_hi[n][0], acc[jj][2 + n]);
#pragma unroll
    for (int jj = 0; jj < 4; jj++)
#pragma unroll
      for (int n = 0; n < 2; n++) acc[jj][2 + n] = mfma16(af[jj][1], b_hi[n][1], acc[jj][2 + n]);
    __builtin_amdgcn_s_setprio(0);
  }

#pragma unroll
  for (int jj = 0; jj < 4; jj++)
#pragma unroll
    for (int n = 0; n < 4; n++) {
      const int col = n0 + (4 * n + wn) * 16 + i;
      const float bv = bias[col];
#pragma unroll
      for (int r = 0; r < 4; r++) {
        const int row = m0 + (2 * jj + wm) * 16 + g * 4 + r;
        epilogue_store<EPI>(acc[jj][n][r] + bv, row, col, Nn, res, outf, outb, oq, ok, ov);
      }
    }
}

// ---------------- causal flash attention (paired q-tiles, swapped QK^T) ----------------
// q,k: (BH, T, 128) bf16; vt: (BH, 128, T) bf16; y: (B, T, C) bf16
__global__ __launch_bounds__(256) void attn_kernel(
    const unsigned short* __restrict__ q, const unsigned short* __restrict__ k,
    const unsigned short* __restrict__ vt, unsigned short* __restrict__ y) {
  __shared__ unsigned short Ks[64 * 128];   // swizzled [kv][hs]
  __shared__ unsigned short Vs[128 * 64];   // swizzled [d][kv]
  __shared__ unsigned short Ps[4][16 * 64]; // per-wave swizzled [q=i][kv]
  const int tid = threadIdx.x, lane = tid & 63, w = tid >> 6;
  const int i = lane & 15, g = lane >> 4;
  const int p = blockIdx.x, bh = blockIdx.y;
  const int q0A = p * 64, q0B = (31 - p) * 64;
  const int tB = 31 - p;
  const size_t hb = (size_t)bh * (2048 * 128);
  const float sc2 = 0.08838834764831845f * 1.44269504088896341f;

  bf16x8 qfA[4], qfB[4];
  {
    const int qra = q0A + w * 16 + i, qrb = q0B + w * 16 + i;
#pragma unroll
    for (int kc = 0; kc < 4; kc++) {
      qfA[kc] = *(const bf16x8*)(q + hb + (size_t)qra * 128 + kc * 32 + g * 8);
      qfB[kc] = *(const bf16x8*)(q + hb + (size_t)qrb * 128 + kc * 32 + g * 8);
    }
  }
  f32x4 oA[8] = {}, oB[8] = {};
  float mA = -__builtin_inff(), lA = 0.f, mB = -__builtin_inff(), lB = 0.f;

  auto proc = [&](const bf16x8 (&qf)[4], f32x4 (&oacc)[8], float& mrun, float& lrun,
                  bool diag) {
    f32x4 st[4];
#pragma unroll
    for (int ct = 0; ct < 4; ct++) {
      f32x4 a = {};
      const int kvr = ct * 16 + i;
#pragma unroll
      for (int kc = 0; kc < 4; kc++) {
        bf16x8 kf = *(const bf16x8*)((char*)Ks + kvr * 256 + (((kc * 4 + g) ^ (i & 7)) << 4));
        a = mfma16(kf, qf[kc], a);
      }
      st[ct] = a;
    }
    float tm = -__builtin_inff();
    const int ql = w * 16 + i;
#pragma unroll
    for (int ct = 0; ct < 4; ct++)
#pragma unroll
      for (int r = 0; r < 4; r++) {
        float v = st[ct][r] * sc2;
        if (diag) {
          const int kvl = ct * 16 + g * 4 + r;
          if (kvl > ql) v = -__builtin_inff();
        }
        st[ct][r] = v;
        tm = fmaxf(tm, v);
      }
    tm = fmaxf(tm, __shfl_xor(tm, 16, 64));
    tm = fmaxf(tm, __shfl_xor(tm, 32, 64));
    if (!__all(tm - mrun <= 8.f)) {
      const float mnew = fmaxf(mrun, tm);
      const float al = exp2fast(mrun - mnew);
      float ar[4];
#pragma unroll
      for (int r = 0; r < 4; r++) ar[r] = __shfl(al, g * 4 + r, 64);
#pragma unroll
      for (int dt = 0; dt < 8; dt++)
#pragma unroll
        for (int r = 0; r < 4; r++) oacc[dt][r] *= ar[r];
      lrun *= al;
      mrun = mnew;
    }
    float ps = 0.f;
#pragma unroll
    for (int ct = 0; ct < 4; ct++)
#pragma unroll
      for (int r = 0; r < 4; r++) {
        const float pv = exp2fast(st[ct][r] - mrun);
        st[ct][r] = pv;
        ps += pv;
      }
    ps += __shfl_xor(ps, 16, 64);
    ps += __shfl_xor(ps, 32, 64);
    lrun += ps;
#pragma unroll
    for (int ct = 0; ct < 4; ct++) {
      unsigned w0, w1;
      asm("v_cvt_pk_bf16_f32 %0, %1, %2" : "=v"(w0) : "v"(st[ct][0]), "v"(st[ct][1]));
      asm("v_cvt_pk_bf16_f32 %0, %1, %2" : "=v"(w1) : "v"(st[ct][2]), "v"(st[ct][3]));
      char* pb = (char*)&Ps[w][0] + i * 128 +
                 ((((2 * ct + (g >> 1)) ^ (i & 7)) << 4) + (g & 1) * 8);
      *(uint2*)pb = make_uint2(w0, w1);
    }
    bf16x8 pf[2];
#pragma unroll
    for (int kvc = 0; kvc < 2; kvc++)
      pf[kvc] = *(const bf16x8*)((char*)&Ps[w][0] + i * 128 + (((kvc * 4 + g) ^ (i & 7)) << 4));
#pragma unroll
    for (int dt = 0; dt < 8; dt++) {
      const int dr = dt * 16 + i;
#pragma unroll
      for (int kvc = 0; kvc < 2; kvc++) {
        bf16x8 vf = *(const bf16x8*)((char*)Vs + dr * 128 + (((kvc * 4 + g) ^ (dr & 7)) << 4));
        oacc[dt] = mfma16(pf[kvc], vf, oacc[dt]);
      }
    }
  };

  for (int t = 0; t <= tB; ++t) {
    const int j0 = t * 64;
    __syncthreads();
#pragma unroll
    for (int it = 0; it < 4; it++) {
      const int ci = it * 256 + tid;
      const int kv = ci >> 4, ccl = ci & 15;
      gload_lds16(k + hb + (size_t)(j0 + kv) * 128 + ((ccl ^ (kv & 7)) << 3),
                  (char*)Ks + (size_t)(it * 256 + w * 64) * 16);
      const int dd = ci >> 3, c2l = ci & 7;
      gload_lds16(vt + hb + (size_t)dd * 2048 + j0 + ((c2l ^ (dd & 7)) << 3),
                  (char*)Vs + (size_t)(it * 256 + w * 64) * 16);
    }
    __syncthreads();
    if (t <= p) proc(qfA, oA, mA, lA, t == p);
    proc(qfB, oB, mB, lB, t == tB);
  }

  const int bb = bh >> 4, hh = bh & 15;
  auto finish = [&](const f32x4 (&oacc)[8], float lrun, int q0s) {
    const float inv_i = 1.f / lrun;
    float ir[4];
#pragma unroll
    for (int r = 0; r < 4; r++) ir[r] = __shfl(inv_i, g * 4 + r, 64);
#pragma unroll
    for (int r = 0; r < 4; r++) {
      const int row = q0s + w * 16 + g * 4 + r;
#pragma unroll
      for (int dt = 0; dt < 8; dt++) {
        const int d = dt * 16 + i;
        y[((size_t)(bb * 2048 + row)) * 2048 + hh * 128 + d] = f2bf(oacc[dt][r] * ir[r]);
      }
    }
  };
  finish(oA, lA, q0A);
  finish(oB, lB, q0B);
}

// ---------------- launcher ----------------
extern "C" void kernel_launch(void* const* d_in, const int* in_sizes, int n_in,
                              void* d_out, int out_size, void* d_ws, size_t ws_size,
                              hipStream_t stream) {
  const float* x      = (const float*)d_in[0];
  const float* ln1_w  = (const float*)d_in[1];
  const float* ln1_b  = (const float*)d_in[2];
  const float* w_qkv  = (const float*)d_in[3];
  const float* b_qkv  = (const float*)d_in[4];
  const float* w_proj = (const float*)d_in[5];
  const float* b_proj = (const float*)d_in[6];
  const float* ln2_w  = (const float*)d_in[7];
  const float* ln2_b  = (const float*)d_in[8];
  const float* w_fc   = (const float*)d_in[9];
  const float* b_fc   = (const float*)d_in[10];
  const float* w_fc2  = (const float*)d_in[11];
  const float* b_fc2  = (const float*)d_in[12];

  char* ws = (char*)d_ws;
  unsigned short* wt_qkv  = (unsigned short*)(ws + 0);          // 25165824 B
  unsigned short* wt_proj = (unsigned short*)(ws + 25165824);   // 8388608
  unsigned short* qb      = (unsigned short*)(ws + 33554432);   // 16777216
  unsigned short* kb      = (unsigned short*)(ws + 50331648);   // 16777216
  unsigned short* wt_fc   = (unsigned short*)(ws + 67108864);   // 33554432
  unsigned short* wt_fc2  = (unsigned short*)(ws + 100663296);  // 33554432
  unsigned short* hb      = (unsigned short*)(ws + 134217728);  // 16777216 (h1/h2)
  unsigned short* vtb     = (unsigned short*)(ws + 150994944);  // 16777216
  unsigned short* yb      = (unsigned short*)(ws + 167772160);  // 16777216 (vb then y)
  float*          x1      = (float*)(ws + 184549376);           // 33554432 (ends 218103808)
  unsigned short* hfc     = (unsigned short*)(ws + 0);          // 67108864, aliases dead wt_qkv/wt_proj/qb/kb
  float* outp = (float*)d_out;

  dim3 tb(32, 8);
  transpose_to_bf16<<<dim3(6144 / 32, 2048 / 32), tb, 0, stream>>>(w_qkv, wt_qkv, 2048, 6144);
  transpose_to_bf16<<<dim3(2048 / 32, 2048 / 32), tb, 0, stream>>>(w_proj, wt_proj, 2048, 2048);
  transpose_to_bf16<<<dim3(8192 / 32, 2048 / 32), tb, 0, stream>>>(w_fc, wt_fc, 2048, 8192);
  transpose_to_bf16<<<dim3(2048 / 32, 8192 / 32), tb, 0, stream>>>(w_fc2, wt_fc2, 8192, 2048);

  ln_kernel<<<4096, 256, 0, stream>>>(x, ln1_w, ln1_b, hb);

  // qkv: 128x256 tiles -> 32x24 = 768 blocks (3 clean rounds)
  gemm128<0><<<768, 512, 0, stream>>>(
      hb, wt_qkv, b_qkv, nullptr, nullptr, nullptr, qb, kb, yb, 6144, 2048, 24);
  transpose_v<<<dim3(2048 / 32, 128 / 32, 32), tb, 0, stream>>>(yb, vtb);

  // paired causal q-tiles: 16 pairs x 32 bh = 512 blocks, uniform work
  attn_kernel<<<dim3(16, 32), 256, 0, stream>>>(qb, kb, vtb, yb);

  // proj + residual -> x1 (f32): 32x8 = 256 blocks (1 clean round)
  gemm128<2><<<256, 512, 0, stream>>>(
      yb, wt_proj, b_proj, x, x1, nullptr, nullptr, nullptr, nullptr, 2048, 2048, 8);

  ln_kernel<<<4096, 256, 0, stream>>>(x1, ln2_w, ln2_b, hb);

  // fc + GELU -> hfc (bf16): 256x256 tiles, 512 blocks (2 clean rounds)
  gemm256<1><<<512, 512, 0, stream>>>(
      hb, wt_fc, b_fc, nullptr, nullptr, hfc, nullptr, nullptr, nullptr, 8192, 2048, 32);

  // fc2 + residual -> out (f32): 32x8 = 256 blocks (1 clean round)
  gemm128<2><<<256, 512, 0, stream>>>(
      hfc, wt_fc2, b_fc2, x1, outp, nullptr, nullptr, nullptr, nullptr, 2048, 8192, 8);
}

// Round 2
// 668.256 us; speedup vs baseline: 1.0899x; 1.0899x over previous
//
#include <hip/hip_runtime.h>
#include <hip/hip_bf16.h>
#include <cstdint>
#include <cstddef>

typedef __attribute__((ext_vector_type(8))) short bf16x8;
typedef __attribute__((ext_vector_type(4))) float f32x4;

#define DEVI __device__ __forceinline__

DEVI unsigned short f2bf(float f) {
  union { float f; unsigned u; } x; x.f = f;
  unsigned r = x.u + 0x7fffu + ((x.u >> 16) & 1u);
  return (unsigned short)(r >> 16);
}

DEVI float exp2fast(float x) {
#if __has_builtin(__builtin_amdgcn_exp2f)
  return __builtin_amdgcn_exp2f(x);
#else
  return exp2f(x);
#endif
}

DEVI void gload_lds16(const void* g, void* l) {
  __builtin_amdgcn_global_load_lds((const __attribute__((address_space(1))) void*)g,
                                   (__attribute__((address_space(3))) void*)l, 16, 0, 0);
}

DEVI f32x4 mfma16(bf16x8 a, bf16x8 b, f32x4 c) {
  return __builtin_amdgcn_mfma_f32_16x16x32_bf16(a, b, c, 0, 0, 0);
}

// ---------------- weight transpose fp32 (K,N) -> bf16 (N,K) ----------------
__global__ __launch_bounds__(256) void transpose_to_bf16(
    const float* __restrict__ w, unsigned short* __restrict__ wt, int K, int N) {
  __shared__ float tile[32][33];
  const int n0 = blockIdx.x * 32, k0 = blockIdx.y * 32;
  const int tx = threadIdx.x, ty = threadIdx.y;
#pragma unroll
  for (int i = 0; i < 4; i++)
    tile[ty + i * 8][tx] = w[(size_t)(k0 + ty + i * 8) * N + n0 + tx];
  __syncthreads();
#pragma unroll
  for (int i = 0; i < 4; i++)
    wt[(size_t)(n0 + ty + i * 8) * K + k0 + tx] = f2bf(tile[tx][ty + i * 8]);
}

// ---------------- bf16 per-head transpose (BH,T,HS) -> (BH,HS,T) ----------------
__global__ __launch_bounds__(256) void transpose_v(
    const unsigned short* __restrict__ in, unsigned short* __restrict__ out) {
  __shared__ unsigned short tile[32][33];
  const int bh = blockIdx.z;
  const unsigned short* inp = in + (size_t)bh * 2048 * 128;
  unsigned short* op = out + (size_t)bh * 2048 * 128;
  const int t0 = blockIdx.x * 32, d0 = blockIdx.y * 32;
  const int tx = threadIdx.x, ty = threadIdx.y;
#pragma unroll
  for (int i = 0; i < 4; i++)
    tile[ty + i * 8][tx] = inp[(size_t)(t0 + ty + i * 8) * 128 + d0 + tx];
  __syncthreads();
#pragma unroll
  for (int i = 0; i < 4; i++)
    op[(size_t)(d0 + ty + i * 8) * 2048 + t0 + tx] = tile[tx][ty + i * 8];
}

// ---------------- LayerNorm: f32 row(2048) -> bf16 ----------------
__global__ __launch_bounds__(256) void ln_kernel(
    const float* __restrict__ x, const float* __restrict__ gw,
    const float* __restrict__ gb, unsigned short* __restrict__ out) {
  __shared__ float red[8];
  const int row = blockIdx.x, tid = threadIdx.x;
  const float* xr = x + (size_t)row * 2048;
  f32x4 a = *((const f32x4*)xr + tid * 2);
  f32x4 b = *((const f32x4*)xr + tid * 2 + 1);
  float s = a[0] + a[1] + a[2] + a[3] + b[0] + b[1] + b[2] + b[3];
#pragma unroll
  for (int m = 32; m >= 1; m >>= 1) s += __shfl_xor(s, m, 64);
  if ((tid & 63) == 0) red[tid >> 6] = s;
  __syncthreads();
  const float mu = (red[0] + red[1] + red[2] + red[3]) * (1.f / 2048.f);
  float d[8]; float ss = 0.f;
#pragma unroll
  for (int j = 0; j < 8; j++) {
    float v = ((j < 4) ? a[j] : b[j - 4]) - mu;
    d[j] = v; ss += v * v;
  }
#pragma unroll
  for (int m = 32; m >= 1; m >>= 1) ss += __shfl_xor(ss, m, 64);
  __syncthreads();
  if ((tid & 63) == 0) red[4 + (tid >> 6)] = ss;
  __syncthreads();
  const float var = (red[4] + red[5] + red[6] + red[7]) * (1.f / 2048.f);
  const float rstd = rsqrtf(var + 1e-5f);
  f32x4 w0 = *((const f32x4*)gw + tid * 2), w1 = *((const f32x4*)gw + tid * 2 + 1);
  f32x4 b0 = *((const f32x4*)gb + tid * 2), b1 = *((const f32x4*)gb + tid * 2 + 1);
  union { bf16x8 v; unsigned short u[8]; } o;
#pragma unroll
  for (int j = 0; j < 8; j++) {
    float wv = (j < 4) ? w0[j] : w1[j - 4];
    float bv = (j < 4) ? b0[j] : b1[j - 4];
    o.u[j] = f2bf(d[j] * rstd * wv + bv);
  }
  *(bf16x8*)(out + (size_t)row * 2048 + tid * 8) = o.v;
}

// =====================================================================
// Shared epilogue: C[row,col] with row = m0+(2jj+wm)*16+g*4+r, col = n0+(4n+wn)*16+i
// EPI 0: QKV scatter to q/k/v head layout bf16; EPI 1: GELU -> bf16; EPI 2: +res -> f32
template <int EPI>
DEVI void epilogue_store(float v, int row, int col, int Nn,
                         const float* __restrict__ res, float* __restrict__ outf,
                         unsigned short* __restrict__ outb, unsigned short* __restrict__ oq,
                         unsigned short* __restrict__ ok, unsigned short* __restrict__ ov) {
  if constexpr (EPI == 0) {
    const int which = col >> 11, cc = col & 2047;
    const int hh = cc >> 7, hs = cc & 127;
    const int bb = row >> 11, tt = row & 2047;
    const size_t bh = (size_t)(bb * 16 + hh);
    const unsigned short bits = f2bf(v);
    if (which == 0) oq[(bh * 2048 + tt) * 128 + hs] = bits;
    else if (which == 1) ok[(bh * 2048 + tt) * 128 + hs] = bits;
    else ov[(bh * 2048 + tt) * 128 + hs] = bits;
  } else if constexpr (EPI == 1) {
    const float ge = 0.5f * v * (1.0f + erff(v * 0.70710678118654752f));
    outb[(size_t)row * Nn + col] = f2bf(ge);
  } else {
    outf[(size_t)row * Nn + col] = v + res[(size_t)row * Nn + col];
  }
}

// ---------------- 256x256 4-phase/K-tile GEMM (used for FC) ----------------
// v3: ONE barrier per phase (pre-MFMA). The post-MFMA barrier is removed so a
// wave finishing its MFMA cluster proceeds (at prio 0) into the next phase's
// ds_reads/staging while its SIMD-mates still issue MFMAs at prio 1.
// Hazard audit (single-barrier): every staged region is vmcnt-drained >=1
// barrier before the phase that ds_reads it; every LDS overwrite is >=3
// barriers after the last in-flight read of that region (p3 has no reads).
template <int EPI>
__global__ __launch_bounds__(512, 2) void gemm256(
    const unsigned short* __restrict__ A, const unsigned short* __restrict__ Bt,
    const float* __restrict__ bias, const float* __restrict__ res,
    float* __restrict__ outf, unsigned short* __restrict__ outb,
    unsigned short* __restrict__ oq, unsigned short* __restrict__ ok,
    unsigned short* __restrict__ ov, int Nn, int Kk, int nbn) {
  __shared__ unsigned short As[2][256 * 64];
  __shared__ unsigned short Bs[2][256 * 64];
  const int tid = threadIdx.x;
  const int lane = tid & 63, wid = tid >> 6;
  const int i = lane & 15, g = lane >> 4;
  const int wm = wid >> 2, wn = wid & 3;
  const int nwg = gridDim.x;
  const int sid = (blockIdx.x & 7) * (nwg >> 3) + (blockIdx.x >> 3);
  const int m0 = (sid / nbn) * 256, n0 = (sid % nbn) * 256;

  auto stageA = [&](int bf, int kt, int h) {
#pragma unroll
    for (int c = 0; c < 2; c++) {
      const int cb = h * 1024 + c * 512 + wid * 64;
      const int ci = cb + lane;
      const int row = ci >> 3;
      const int kc = (ci & 7) ^ (row & 7);
      gload_lds16(A + (size_t)(m0 + row) * Kk + kt + kc * 8, &As[bf][(size_t)cb * 8]);
    }
  };
  auto stageB = [&](int bf, int kt, int h) {
#pragma unroll
    for (int c = 0; c < 2; c++) {
      const int cb = h * 1024 + c * 512 + wid * 64;
      const int ci = cb + lane;
      const int row = ci >> 3;
      const int kc = (ci & 7) ^ (row & 7);
      gload_lds16(Bt + (size_t)(n0 + row) * Kk + kt + kc * 8, &Bs[bf][(size_t)cb * 8]);
    }
  };
  auto ldA = [&](int bf, int jj, int ks) -> bf16x8 {
    const int row = (2 * jj + wm) * 16 + i;
    return *(const bf16x8*)((const char*)&As[bf][0] + row * 128 + ((((ks << 2) + g) ^ (i & 7)) << 4));
  };
  auto ldB = [&](int bf, int n, int ks) -> bf16x8 {
    const int row = (4 * n + wn) * 16 + i;
    return *(const bf16x8*)((const char*)&Bs[bf][0] + row * 128 + ((((ks << 2) + g) ^ (i & 7)) << 4));
  };

  f32x4 acc[8][4] = {};
  const int NT = Kk >> 6;

  stageA(0, 0, 0);
  stageB(0, 0, 0);
  stageB(0, 0, 1);
  stageA(0, 0, 1);
  asm volatile("s_waitcnt vmcnt(4)" ::: "memory");
  __builtin_amdgcn_s_barrier();
  __builtin_amdgcn_sched_barrier(0);

  bf16x8 a_lo[4][2], a_hi[4][2], b_lo[2][2], b_hi[2][2];
  for (int t = 0; t < NT; ++t) {
    const int cur = t & 1, nxt = cur ^ 1;
    const int ktn = (t + 1) << 6;
    const bool hn = (t + 1) < NT;
    // phase 0: read a_lo,b_lo(cur); stage A-h0(nxt); drain B-h1(cur)
#pragma unroll
    for (int jj = 0; jj < 4; jj++) { a_lo[jj][0] = ldA(cur, jj, 0); a_lo[jj][1] = ldA(cur, jj, 1); }
#pragma unroll
    for (int n = 0; n < 2; n++) { b_lo[n][0] = ldB(cur, n, 0); b_lo[n][1] = ldB(cur, n, 1); }
    if (hn) stageA(nxt, ktn, 0);
    if (hn) asm volatile("s_waitcnt vmcnt(4)" ::: "memory");
    else    asm volatile("s_waitcnt vmcnt(2)" ::: "memory");
    __builtin_amdgcn_s_barrier();
    asm volatile("s_waitcnt lgkmcnt(0)" ::: "memory");
    __builtin_amdgcn_sched_barrier(0);
    __builtin_amdgcn_s_setprio(1);
#pragma unroll
    for (int jj = 0; jj < 4; jj++)
#pragma unroll
      for (int n = 0; n < 2; n++) {
        acc[jj][n] = mfma16(a_lo[jj][0], b_lo[n][0], acc[jj][n]);
        acc[jj][n] = mfma16(a_lo[jj][1], b_lo[n][1], acc[jj][n]);
      }
    __builtin_amdgcn_s_setprio(0);
    // phase 1: read b_hi(cur); stage B-h0(nxt); drain A-h1(cur)
#pragma unroll
    for (int n = 0; n < 2; n++) { b_hi[n][0] = ldB(cur, 2 + n, 0); b_hi[n][1] = ldB(cur, 2 + n, 1); }
    if (hn) stageB(nxt, ktn, 0);
    if (hn) asm volatile("s_waitcnt vmcnt(4)" ::: "memory");
    else    asm volatile("s_waitcnt vmcnt(0)" ::: "memory");
    __builtin_amdgcn_s_barrier();
    asm volatile("s_waitcnt lgkmcnt(0)" ::: "memory");
    __builtin_amdgcn_sched_barrier(0);
    __builtin_amdgcn_s_setprio(1);
#pragma unroll
    for (int jj = 0; jj < 4; jj++)
#pragma unroll
      for (int n = 0; n < 2; n++) {
        acc[jj][2 + n] = mfma16(a_lo[jj][0], b_hi[n][0], acc[jj][2 + n]);
        acc[jj][2 + n] = mfma16(a_lo[jj][1], b_hi[n][1], acc[jj][2 + n]);
      }
    __builtin_amdgcn_s_setprio(0);
    // phase 2: read a_hi(cur); stage B-h1(nxt); no wait
#pragma unroll
    for (int jj = 0; jj < 4; jj++) { a_hi[jj][0] = ldA(cur, 4 + jj, 0); a_hi[jj][1] = ldA(cur, 4 + jj, 1); }
    if (hn) stageB(nxt, ktn, 1);
    __builtin_amdgcn_s_barrier();
    asm volatile("s_waitcnt lgkmcnt(0)" ::: "memory");
    __builtin_amdgcn_sched_barrier(0);
    __builtin_amdgcn_s_setprio(1);
#pragma unroll
    for (int jj = 0; jj < 4; jj++)
#pragma unroll
      for (int n = 0; n < 2; n++) {
        acc[4 + jj][n] = mfma16(a_hi[jj][0], b_lo[n][0], acc[4 + jj][n]);
        acc[4 + jj][n] = mfma16(a_hi[jj][1], b_lo[n][1], acc[4 + jj][n]);
      }
    __builtin_amdgcn_s_setprio(0);
    // phase 3: no reads; stage A-h1(nxt); drain A-h0,B-h0(nxt)
    if (hn) stageA(nxt, ktn, 1);
    if (hn) asm volatile("s_waitcnt vmcnt(4)" ::: "memory");
    __builtin_amdgcn_s_barrier();
    asm volatile("s_waitcnt lgkmcnt(0)" ::: "memory");
    __builtin_amdgcn_sched_barrier(0);
    __builtin_amdgcn_s_setprio(1);
#pragma unroll
    for (int jj = 0; jj < 4; jj++)
#pragma unroll
      for (int n = 0; n < 2; n++) {
        acc[4 + jj][2 + n] = mfma16(a_hi[jj][0], b_hi[n][0], acc[4 + jj][2 + n]);
        acc[4 + jj][2 + n] = mfma16(a_hi[jj][1], b_hi[n][1], acc[4 + jj][2 + n]);
      }
    __builtin_amdgcn_s_setprio(0);
  }

#pragma unroll
  for (int jj = 0; jj < 8; jj++)
#pragma unroll
    for (int n = 0; n < 4; n++) {
      const int col = n0 + (4 * n + wn) * 16 + i;
      const float bv = bias[col];
#pragma unroll
      for (int r = 0; r < 4; r++) {
        const int row = m0 + (2 * jj + wm) * 16 + g * 4 + r;
        epilogue_store<EPI>(acc[jj][n][r] + bv, row, col, Nn, res, outf, outb, oq, ok, ov);
      }
    }
}

// ---------------- 128x256 2-phase/K-tile GEMM (QKV / proj / FC2) ----------------
// v3: single barrier per phase. Restaged for WAR safety under single-barrier:
// p0 stages A+B-h0(nxt) [4 loads], p1 stages B-h1(nxt) [2 loads], so the
// tile-boundary stage never overwrites a region with possibly in-flight reads.
// Waits: p0 vmcnt(4) drains B-h1(cur) (read at p1, barrier between);
//        p1 vmcnt(2) drains A,B-h0(nxt) (read at t+1 p0, barrier between).
template <int EPI>
__global__ __launch_bounds__(512, 2) void gemm128(
    const unsigned short* __restrict__ A, const unsigned short* __restrict__ Bt,
    const float* __restrict__ bias, const float* __restrict__ res,
    float* __restrict__ outf, unsigned short* __restrict__ outb,
    unsigned short* __restrict__ oq, unsigned short* __restrict__ ok,
    unsigned short* __restrict__ ov, int Nn, int Kk, int nbn) {
  __shared__ unsigned short As[2][128 * 64];   // 32 KiB
  __shared__ unsigned short Bs[2][256 * 64];   // 64 KiB
  const int tid = threadIdx.x;
  const int lane = tid & 63, wid = tid >> 6;
  const int i = lane & 15, g = lane >> 4;
  const int wm = wid >> 2, wn = wid & 3;
  const int nwg = gridDim.x;
  const int sid = (blockIdx.x & 7) * (nwg >> 3) + (blockIdx.x >> 3);
  const int m0 = (sid / nbn) * 128, n0 = (sid % nbn) * 256;

  auto stageA = [&](int bf, int kt) {
#pragma unroll
    for (int c = 0; c < 2; c++) {
      const int cb = c * 512 + wid * 64;
      const int ci = cb + lane;
      const int row = ci >> 3;
      const int kc = (ci & 7) ^ (row & 7);
      gload_lds16(A + (size_t)(m0 + row) * Kk + kt + kc * 8, &As[bf][(size_t)cb * 8]);
    }
  };
  auto stageB = [&](int bf, int kt, int h) {
#pragma unroll
    for (int c = 0; c < 2; c++) {
      const int cb = h * 1024 + c * 512 + wid * 64;
      const int ci = cb + lane;
      const int row = ci >> 3;
      const int kc = (ci & 7) ^ (row & 7);
      gload_lds16(Bt + (size_t)(n0 + row) * Kk + kt + kc * 8, &Bs[bf][(size_t)cb * 8]);
    }
  };
  auto ldA = [&](int bf, int jj, int ks) -> bf16x8 {
    const int row = (2 * jj + wm) * 16 + i;
    return *(const bf16x8*)((const char*)&As[bf][0] + row * 128 + ((((ks << 2) + g) ^ (i & 7)) << 4));
  };
  auto ldB = [&](int bf, int n, int ks) -> bf16x8 {
    const int row = (4 * n + wn) * 16 + i;
    return *(const bf16x8*)((const char*)&Bs[bf][0] + row * 128 + ((((ks << 2) + g) ^ (i & 7)) << 4));
  };

  f32x4 acc[4][4] = {};
  const int NT = Kk >> 6;

  stageA(0, 0);
  stageB(0, 0, 0);
  stageB(0, 0, 1);
  asm volatile("s_waitcnt vmcnt(2)" ::: "memory");
  __builtin_amdgcn_s_barrier();
  __builtin_amdgcn_sched_barrier(0);

  bf16x8 af[4][2], b_lo[2][2], b_hi[2][2];
  for (int t = 0; t < NT; ++t) {
    const int cur = t & 1, nxt = cur ^ 1;
    const int ktn = (t + 1) << 6;
    const bool hn = (t + 1) < NT;
    // ---- PH0: read af,b_lo(cur); stage A+B-h0(nxt); drain B-h1(cur)
#pragma unroll
    for (int jj = 0; jj < 4; jj++) { af[jj][0] = ldA(cur, jj, 0); af[jj][1] = ldA(cur, jj, 1); }
#pragma unroll
    for (int n = 0; n < 2; n++) { b_lo[n][0] = ldB(cur, n, 0); b_lo[n][1] = ldB(cur, n, 1); }
    if (hn) { stageA(nxt, ktn); stageB(nxt, ktn, 0); }
    if (hn) asm volatile("s_waitcnt vmcnt(4)" ::: "memory");
    else    asm volatile("s_waitcnt vmcnt(0)" ::: "memory");
    __builtin_amdgcn_s_barrier();
    asm volatile("s_waitcnt lgkmcnt(0)" ::: "memory");
    __builtin_amdgcn_sched_barrier(0);
    __builtin_amdgcn_s_setprio(1);
#pragma unroll
    for (int jj = 0; jj < 4; jj++)
#pragma unroll
      for (int n = 0; n < 2; n++) {
        acc[jj][n] = mfma16(af[jj][0], b_lo[n][0], acc[jj][n]);
        acc[jj][n] = mfma16(af[jj][1], b_lo[n][1], acc[jj][n]);
      }
    __builtin_amdgcn_s_setprio(0);
    // ---- PH1: read b_hi(cur); stage B-h1(nxt); drain A,B-h0(nxt)
#pragma unroll
    for (int n = 0; n < 2; n++) { b_hi[n][0] = ldB(cur, 2 + n, 0); b_hi[n][1] = ldB(cur, 2 + n, 1); }
    if (hn) stageB(nxt, ktn, 1);
    if (hn) asm volatile("s_waitcnt vmcnt(2)" ::: "memory");
    __builtin_amdgcn_s_barrier();
    asm volatile("s_waitcnt lgkmcnt(0)" ::: "memory");
    __builtin_amdgcn_sched_barrier(0);
    __builtin_amdgcn_s_setprio(1);
#pragma unroll
    for (int jj = 0; jj < 4; jj++)
#pragma unroll
      for (int n = 0; n < 2; n++) {
        acc[jj][2 + n] = mfma16(af[jj][0], b_hi[n][0], acc[jj][2 + n]);
        acc[jj][2 + n] = mfma16(af[jj][1], b_hi[n][1], acc[jj][2 + n]);
      }
    __builtin_amdgcn_s_setprio(0);
  }

#pragma unroll
  for (int jj = 0; jj < 4; jj++)
#pragma unroll
    for (int n = 0; n < 4; n++) {
      const int col = n0 + (4 * n + wn) * 16 + i;
      const float bv = bias[col];
#pragma unroll
      for (int r = 0; r < 4; r++) {
        const int row = m0 + (2 * jj + wm) * 16 + g * 4 + r;
        epilogue_store<EPI>(acc[jj][n][r] + bv, row, col, Nn, res, outf, outb, oq, ok, ov);
      }
    }
}

// ---------------- causal flash attention (paired q-tiles, swapped QK^T) ----------------
// q,k: (BH, T, 128) bf16; vt: (BH, 128, T) bf16; y: (B, T, C) bf16
__global__ __launch_bounds__(256) void attn_kernel(
    const unsigned short* __restrict__ q, const unsigned short* __restrict__ k,
    const unsigned short* __restrict__ vt, unsigned short* __restrict__ y) {
  __shared__ unsigned short Ks[64 * 128];   // swizzled [kv][hs]
  __shared__ unsigned short Vs[128 * 64];   // swizzled [d][kv]
  __shared__ unsigned short Ps[4][16 * 64]; // per-wave swizzled [q=i][kv]
  const int tid = threadIdx.x, lane = tid & 63, w = tid >> 6;
  const int i = lane & 15, g = lane >> 4;
  const int p = blockIdx.x, bh = blockIdx.y;
  const int q0A = p * 64, q0B = (31 - p) * 64;
  const int tB = 31 - p;
  const size_t hb = (size_t)bh * (2048 * 128);
  const float sc2 = 0.08838834764831845f * 1.44269504088896341f;

  bf16x8 qfA[4], qfB[4];
  {
    const int qra = q0A + w * 16 + i, qrb = q0B + w * 16 + i;
#pragma unroll
    for (int kc = 0; kc < 4; kc++) {
      qfA[kc] = *(const bf16x8*)(q + hb + (size_t)qra * 128 + kc * 32 + g * 8);
      qfB[kc] = *(const bf16x8*)(q + hb + (size_t)qrb * 128 + kc * 32 + g * 8);
    }
  }
  f32x4 oA[8] = {}, oB[8] = {};
  float mA = -__builtin_inff(), lA = 0.f, mB = -__builtin_inff(), lB = 0.f;

  auto proc = [&](const bf16x8 (&qf)[4], f32x4 (&oacc)[8], float& mrun, float& lrun,
                  bool diag) {
    f32x4 st[4];
#pragma unroll
    for (int ct = 0; ct < 4; ct++) {
      f32x4 a = {};
      const int kvr = ct * 16 + i;
#pragma unroll
      for (int kc = 0; kc < 4; kc++) {
        bf16x8 kf = *(const bf16x8*)((char*)Ks + kvr * 256 + (((kc * 4 + g) ^ (i & 7)) << 4));
        a = mfma16(kf, qf[kc], a);
      }
      st[ct] = a;
    }
    float tm = -__builtin_inff();
    const int ql = w * 16 + i;
#pragma unroll
    for (int ct = 0; ct < 4; ct++)
#pragma unroll
      for (int r = 0; r < 4; r++) {
        float v = st[ct][r] * sc2;
        if (diag) {
          const int kvl = ct * 16 + g * 4 + r;
          if (kvl > ql) v = -__builtin_inff();
        }
        st[ct][r] = v;
        tm = fmaxf(tm, v);
      }
    tm = fmaxf(tm, __shfl_xor(tm, 16, 64));
    tm = fmaxf(tm, __shfl_xor(tm, 32, 64));
    if (!__all(tm - mrun <= 8.f)) {
      const float mnew = fmaxf(mrun, tm);
      const float al = exp2fast(mrun - mnew);
      float ar[4];
#pragma unroll
      for (int r = 0; r < 4; r++) ar[r] = __shfl(al, g * 4 + r, 64);
#pragma unroll
      for (int dt = 0; dt < 8; dt++)
#pragma unroll
        for (int r = 0; r < 4; r++) oacc[dt][r] *= ar[r];
      lrun *= al;
      mrun = mnew;
    }
    float ps = 0.f;
#pragma unroll
    for (int ct = 0; ct < 4; ct++)
#pragma unroll
      for (int r = 0; r < 4; r++) {
        const float pv = exp2fast(st[ct][r] - mrun);
        st[ct][r] = pv;
        ps += pv;
      }
    ps += __shfl_xor(ps, 16, 64);
    ps += __shfl_xor(ps, 32, 64);
    lrun += ps;
#pragma unroll
    for (int ct = 0; ct < 4; ct++) {
      unsigned w0, w1;
      asm("v_cvt_pk_bf16_f32 %0, %1, %2" : "=v"(w0) : "v"(st[ct][0]), "v"(st[ct][1]));
      asm("v_cvt_pk_bf16_f32 %0, %1, %2" : "=v"(w1) : "v"(st[ct][2]), "v"(st[ct][3]));
      char* pb = (char*)&Ps[w][0] + i * 128 +
                 ((((2 * ct + (g >> 1)) ^ (i & 7)) << 4) + (g & 1) * 8);
      *(uint2*)pb = make_uint2(w0, w1);
    }
    bf16x8 pf[2];
#pragma unroll
    for (int kvc = 0; kvc < 2; kvc++)
      pf[kvc] = *(const bf16x8*)((char*)&Ps[w][0] + i * 128 + (((kvc * 4 + g) ^ (i & 7)) << 4));
#pragma unroll
    for (int dt = 0; dt < 8; dt++) {
      const int dr = dt * 16 + i;
#pragma unroll
      for (int kvc = 0; kvc < 2; kvc++) {
        bf16x8 vf = *(const bf16x8*)((char*)Vs + dr * 128 + (((kvc * 4 + g) ^ (dr & 7)) << 4));
        oacc[dt] = mfma16(pf[kvc], vf, oacc[dt]);
      }
    }
  };

  for (int t = 0; t <= tB; ++t) {
    const int j0 = t * 64;
    __syncthreads();
#pragma unroll
    for (int it = 0; it < 4; it++) {
      const int ci = it * 256 + tid;
      const int kv = ci >> 4, ccl = ci & 15;
      gload_lds16(k + hb + (size_t)(j0 + kv) * 128 + ((ccl ^ (kv & 7)) << 3),
                  (char*)Ks + (size_t)(it * 256 + w * 64) * 16);
      const int dd = ci >> 3, c2l = ci & 7;
      gload_lds16(vt + hb + (size_t)dd * 2048 + j0 + ((c2l ^ (dd & 7)) << 3),
                  (char*)Vs + (size_t)(it * 256 + w * 64) * 16);
    }
    __syncthreads();
    if (t <= p) proc(qfA, oA, mA, lA, t == p);
    proc(qfB, oB, mB, lB, t == tB);
  }

  const int bb = bh >> 4, hh = bh & 15;
  auto finish = [&](const f32x4 (&oacc)[8], float lrun, int q0s) {
    const float inv_i = 1.f / lrun;
    float ir[4];
#pragma unroll
    for (int r = 0; r < 4; r++) ir[r] = __shfl(inv_i, g * 4 + r, 64);
#pragma unroll
    for (int r = 0; r < 4; r++) {
      const int row = q0s + w * 16 + g * 4 + r;
#pragma unroll
      for (int dt = 0; dt < 8; dt++) {
        const int d = dt * 16 + i;
        y[((size_t)(bb * 2048 + row)) * 2048 + hh * 128 + d] = f2bf(oacc[dt][r] * ir[r]);
      }
    }
  };
  finish(oA, lA, q0A);
  finish(oB, lB, q0B);
}

// ---------------- launcher ----------------
extern "C" void kernel_launch(void* const* d_in, const int* in_sizes, int n_in,
                              void* d_out, int out_size, void* d_ws, size_t ws_size,
                              hipStream_t stream) {
  const float* x      = (const float*)d_in[0];
  const float* ln1_w  = (const float*)d_in[1];
  const float* ln1_b  = (const float*)d_in[2];
  const float* w_qkv  = (const float*)d_in[3];
  const float* b_qkv  = (const float*)d_in[4];
  const float* w_proj = (const float*)d_in[5];
  const float* b_proj = (const float*)d_in[6];
  const float* ln2_w  = (const float*)d_in[7];
  const float* ln2_b  = (const float*)d_in[8];
  const float* w_fc   = (const float*)d_in[9];
  const float* b_fc   = (const float*)d_in[10];
  const float* w_fc2  = (const float*)d_in[11];
  const float* b_fc2  = (const float*)d_in[12];

  char* ws = (char*)d_ws;
  unsigned short* wt_qkv  = (unsigned short*)(ws + 0);          // 25165824 B
  unsigned short* wt_proj = (unsigned short*)(ws + 25165824);   // 8388608
  unsigned short* qb      = (unsigned short*)(ws + 33554432);   // 16777216
  unsigned short* kb      = (unsigned short*)(ws + 50331648);   // 16777216
  unsigned short* wt_fc   = (unsigned short*)(ws + 67108864);   // 33554432
  unsigned short* wt_fc2  = (unsigned short*)(ws + 100663296);  // 33554432
  unsigned short* hb      = (unsigned short*)(ws + 134217728);  // 16777216 (h1/h2)
  unsigned short* vtb     = (unsigned short*)(ws + 150994944);  // 16777216
  unsigned short* yb      = (unsigned short*)(ws + 167772160);  // 16777216 (vb then y)
  float*          x1      = (float*)(ws + 184549376);           // 33554432 (ends 218103808)
  unsigned short* hfc     = (unsigned short*)(ws + 0);          // 67108864, aliases dead wt_qkv/wt_proj/qb/kb
  float* outp = (float*)d_out;

  dim3 tb(32, 8);
  transpose_to_bf16<<<dim3(6144 / 32, 2048 / 32), tb, 0, stream>>>(w_qkv, wt_qkv, 2048, 6144);
  transpose_to_bf16<<<dim3(2048 / 32, 2048 / 32), tb, 0, stream>>>(w_proj, wt_proj, 2048, 2048);
  transpose_to_bf16<<<dim3(8192 / 32, 2048 / 32), tb, 0, stream>>>(w_fc, wt_fc, 2048, 8192);
  transpose_to_bf16<<<dim3(2048 / 32, 8192 / 32), tb, 0, stream>>>(w_fc2, wt_fc2, 8192, 2048);

  ln_kernel<<<4096, 256, 0, stream>>>(x, ln1_w, ln1_b, hb);

  // qkv: 128x256 tiles -> 32x24 = 768 blocks (3 clean rounds)
  gemm128<0><<<768, 512, 0, stream>>>(
      hb, wt_qkv, b_qkv, nullptr, nullptr, nullptr, qb, kb, yb, 6144, 2048, 24);
  transpose_v<<<dim3(2048 / 32, 128 / 32, 32), tb, 0, stream>>>(yb, vtb);

  // paired causal q-tiles: 16 pairs x 32 bh = 512 blocks, uniform work
  attn_kernel<<<dim3(16, 32), 256, 0, stream>>>(qb, kb, vtb, yb);

  // proj + residual -> x1 (f32): 32x8 = 256 blocks (1 clean round)
  gemm128<2><<<256, 512, 0, stream>>>(
      yb, wt_proj, b_proj, x, x1, nullptr, nullptr, nullptr, nullptr, 2048, 2048, 8);

  ln_kernel<<<4096, 256, 0, stream>>>(x1, ln2_w, ln2_b, hb);

  // fc + GELU -> hfc (bf16): 256x256 tiles, 512 blocks (2 clean rounds)
  gemm256<1><<<512, 512, 0, stream>>>(
      hb, wt_fc, b_fc, nullptr, nullptr, hfc, nullptr, nullptr, nullptr, 8192, 2048, 32);

  // fc2 + residual -> out (f32): 32x8 = 256 blocks (1 clean round)
  gemm128<2><<<256, 512, 0, stream>>>(
      hfc, wt_fc2, b_fc2, x1, outp, nullptr, nullptr, nullptr, nullptr, 2048, 8192, 8);
}

// Round 3
// 664.653 us; speedup vs baseline: 1.0959x; 1.0054x over previous
//
#include <hip/hip_runtime.h>
#include <hip/hip_bf16.h>
#include <cstdint>
#include <cstddef>

typedef __attribute__((ext_vector_type(8))) short bf16x8;
typedef __attribute__((ext_vector_type(4))) float f32x4;

#define DEVI __device__ __forceinline__

DEVI unsigned short f2bf(float f) {
  union { float f; unsigned u; } x; x.f = f;
  unsigned r = x.u + 0x7fffu + ((x.u >> 16) & 1u);
  return (unsigned short)(r >> 16);
}

DEVI float exp2fast(float x) {
#if __has_builtin(__builtin_amdgcn_exp2f)
  return __builtin_amdgcn_exp2f(x);
#else
  return exp2f(x);
#endif
}

DEVI void gload_lds16(const void* g, void* l) {
  __builtin_amdgcn_global_load_lds((const __attribute__((address_space(1))) void*)g,
                                   (__attribute__((address_space(3))) void*)l, 16, 0, 0);
}

DEVI f32x4 mfma16(bf16x8 a, bf16x8 b, f32x4 c) {
  return __builtin_amdgcn_mfma_f32_16x16x32_bf16(a, b, c, 0, 0, 0);
}

// ---------------- weight transpose fp32 (K,N) -> bf16 (N,K) ----------------
__global__ __launch_bounds__(256) void transpose_to_bf16(
    const float* __restrict__ w, unsigned short* __restrict__ wt, int K, int N) {
  __shared__ float tile[32][33];
  const int n0 = blockIdx.x * 32, k0 = blockIdx.y * 32;
  const int tx = threadIdx.x, ty = threadIdx.y;
#pragma unroll
  for (int i = 0; i < 4; i++)
    tile[ty + i * 8][tx] = w[(size_t)(k0 + ty + i * 8) * N + n0 + tx];
  __syncthreads();
#pragma unroll
  for (int i = 0; i < 4; i++)
    wt[(size_t)(n0 + ty + i * 8) * K + k0 + tx] = f2bf(tile[tx][ty + i * 8]);
}

// ---------------- bf16 per-head transpose (BH,T,HS) -> (BH,HS,T) ----------------
__global__ __launch_bounds__(256) void transpose_v(
    const unsigned short* __restrict__ in, unsigned short* __restrict__ out) {
  __shared__ unsigned short tile[32][33];
  const int bh = blockIdx.z;
  const unsigned short* inp = in + (size_t)bh * 2048 * 128;
  unsigned short* op = out + (size_t)bh * 2048 * 128;
  const int t0 = blockIdx.x * 32, d0 = blockIdx.y * 32;
  const int tx = threadIdx.x, ty = threadIdx.y;
#pragma unroll
  for (int i = 0; i < 4; i++)
    tile[ty + i * 8][tx] = inp[(size_t)(t0 + ty + i * 8) * 128 + d0 + tx];
  __syncthreads();
#pragma unroll
  for (int i = 0; i < 4; i++)
    op[(size_t)(d0 + ty + i * 8) * 2048 + t0 + tx] = tile[tx][ty + i * 8];
}

// ---------------- LayerNorm: f32 row(2048) -> bf16 ----------------
__global__ __launch_bounds__(256) void ln_kernel(
    const float* __restrict__ x, const float* __restrict__ gw,
    const float* __restrict__ gb, unsigned short* __restrict__ out) {
  __shared__ float red[8];
  const int row = blockIdx.x, tid = threadIdx.x;
  const float* xr = x + (size_t)row * 2048;
  f32x4 a = *((const f32x4*)xr + tid * 2);
  f32x4 b = *((const f32x4*)xr + tid * 2 + 1);
  float s = a[0] + a[1] + a[2] + a[3] + b[0] + b[1] + b[2] + b[3];
#pragma unroll
  for (int m = 32; m >= 1; m >>= 1) s += __shfl_xor(s, m, 64);
  if ((tid & 63) == 0) red[tid >> 6] = s;
  __syncthreads();
  const float mu = (red[0] + red[1] + red[2] + red[3]) * (1.f / 2048.f);
  float d[8]; float ss = 0.f;
#pragma unroll
  for (int j = 0; j < 8; j++) {
    float v = ((j < 4) ? a[j] : b[j - 4]) - mu;
    d[j] = v; ss += v * v;
  }
#pragma unroll
  for (int m = 32; m >= 1; m >>= 1) ss += __shfl_xor(ss, m, 64);
  __syncthreads();
  if ((tid & 63) == 0) red[4 + (tid >> 6)] = ss;
  __syncthreads();
  const float var = (red[4] + red[5] + red[6] + red[7]) * (1.f / 2048.f);
  const float rstd = rsqrtf(var + 1e-5f);
  f32x4 w0 = *((const f32x4*)gw + tid * 2), w1 = *((const f32x4*)gw + tid * 2 + 1);
  f32x4 b0 = *((const f32x4*)gb + tid * 2), b1 = *((const f32x4*)gb + tid * 2 + 1);
  union { bf16x8 v; unsigned short u[8]; } o;
#pragma unroll
  for (int j = 0; j < 8; j++) {
    float wv = (j < 4) ? w0[j] : w1[j - 4];
    float bv = (j < 4) ? b0[j] : b1[j - 4];
    o.u[j] = f2bf(d[j] * rstd * wv + bv);
  }
  *(bf16x8*)(out + (size_t)row * 2048 + tid * 8) = o.v;
}

// =====================================================================
// Shared epilogue: C[row,col] with row = m0+(2jj+wm)*16+g*4+r, col = n0+(4n+wn)*16+i
// EPI 0: QKV scatter to q/k/v head layout bf16; EPI 1: GELU -> bf16; EPI 2: +res -> f32
template <int EPI>
DEVI void epilogue_store(float v, int row, int col, int Nn,
                         const float* __restrict__ res, float* __restrict__ outf,
                         unsigned short* __restrict__ outb, unsigned short* __restrict__ oq,
                         unsigned short* __restrict__ ok, unsigned short* __restrict__ ov) {
  if constexpr (EPI == 0) {
    const int which = col >> 11, cc = col & 2047;
    const int hh = cc >> 7, hs = cc & 127;
    const int bb = row >> 11, tt = row & 2047;
    const size_t bh = (size_t)(bb * 16 + hh);
    const unsigned short bits = f2bf(v);
    if (which == 0) oq[(bh * 2048 + tt) * 128 + hs] = bits;
    else if (which == 1) ok[(bh * 2048 + tt) * 128 + hs] = bits;
    else ov[(bh * 2048 + tt) * 128 + hs] = bits;
  } else if constexpr (EPI == 1) {
    const float ge = 0.5f * v * (1.0f + erff(v * 0.70710678118654752f));
    outb[(size_t)row * Nn + col] = f2bf(ge);
  } else {
    outf[(size_t)row * Nn + col] = v + res[(size_t)row * Nn + col];
  }
}

// ---------------- 256x256 4-phase/K-tile GEMM (used for FC) ----------------
// v4: single barrier per phase (v3) + REMOVED the blanket lgkmcnt(0) before
// each MFMA cluster. The ds_reads feed MFMA via compiler-tracked data deps,
// so hipcc emits minimal counted lgkmcnt(N) per dependent MFMA: each wave
// starts MFMA as soon as its first fragments land (4-step staircase) instead
// of draining the whole 12-read burst. Reads reordered into consumption
// order (B first, then A ascending). vmcnt/barrier schedule unchanged
// (cross-wave DMA visibility still vmcnt-drain + barrier).
template <int EPI>
__global__ __launch_bounds__(512, 2) void gemm256(
    const unsigned short* __restrict__ A, const unsigned short* __restrict__ Bt,
    const float* __restrict__ bias, const float* __restrict__ res,
    float* __restrict__ outf, unsigned short* __restrict__ outb,
    unsigned short* __restrict__ oq, unsigned short* __restrict__ ok,
    unsigned short* __restrict__ ov, int Nn, int Kk, int nbn) {
  __shared__ unsigned short As[2][256 * 64];
  __shared__ unsigned short Bs[2][256 * 64];
  const int tid = threadIdx.x;
  const int lane = tid & 63, wid = tid >> 6;
  const int i = lane & 15, g = lane >> 4;
  const int wm = wid >> 2, wn = wid & 3;
  const int nwg = gridDim.x;
  const int sid = (blockIdx.x & 7) * (nwg >> 3) + (blockIdx.x >> 3);
  const int m0 = (sid / nbn) * 256, n0 = (sid % nbn) * 256;

  auto stageA = [&](int bf, int kt, int h) {
#pragma unroll
    for (int c = 0; c < 2; c++) {
      const int cb = h * 1024 + c * 512 + wid * 64;
      const int ci = cb + lane;
      const int row = ci >> 3;
      const int kc = (ci & 7) ^ (row & 7);
      gload_lds16(A + (size_t)(m0 + row) * Kk + kt + kc * 8, &As[bf][(size_t)cb * 8]);
    }
  };
  auto stageB = [&](int bf, int kt, int h) {
#pragma unroll
    for (int c = 0; c < 2; c++) {
      const int cb = h * 1024 + c * 512 + wid * 64;
      const int ci = cb + lane;
      const int row = ci >> 3;
      const int kc = (ci & 7) ^ (row & 7);
      gload_lds16(Bt + (size_t)(n0 + row) * Kk + kt + kc * 8, &Bs[bf][(size_t)cb * 8]);
    }
  };
  auto ldA = [&](int bf, int jj, int ks) -> bf16x8 {
    const int row = (2 * jj + wm) * 16 + i;
    return *(const bf16x8*)((const char*)&As[bf][0] + row * 128 + ((((ks << 2) + g) ^ (i & 7)) << 4));
  };
  auto ldB = [&](int bf, int n, int ks) -> bf16x8 {
    const int row = (4 * n + wn) * 16 + i;
    return *(const bf16x8*)((const char*)&Bs[bf][0] + row * 128 + ((((ks << 2) + g) ^ (i & 7)) << 4));
  };

  f32x4 acc[8][4] = {};
  const int NT = Kk >> 6;

  stageA(0, 0, 0);
  stageB(0, 0, 0);
  stageB(0, 0, 1);
  stageA(0, 0, 1);
  asm volatile("s_waitcnt vmcnt(4)" ::: "memory");
  __builtin_amdgcn_s_barrier();
  __builtin_amdgcn_sched_barrier(0);

  bf16x8 a_lo[4][2], a_hi[4][2], b_lo[2][2], b_hi[2][2];
  for (int t = 0; t < NT; ++t) {
    const int cur = t & 1, nxt = cur ^ 1;
    const int ktn = (t + 1) << 6;
    const bool hn = (t + 1) < NT;
    // phase 0: read b_lo,a_lo(cur); stage A-h0(nxt); drain B-h1(cur)
#pragma unroll
    for (int n = 0; n < 2; n++) { b_lo[n][0] = ldB(cur, n, 0); b_lo[n][1] = ldB(cur, n, 1); }
#pragma unroll
    for (int jj = 0; jj < 4; jj++) { a_lo[jj][0] = ldA(cur, jj, 0); a_lo[jj][1] = ldA(cur, jj, 1); }
    if (hn) stageA(nxt, ktn, 0);
    if (hn) asm volatile("s_waitcnt vmcnt(4)" ::: "memory");
    else    asm volatile("s_waitcnt vmcnt(2)" ::: "memory");
    __builtin_amdgcn_s_barrier();
    __builtin_amdgcn_sched_barrier(0);
    __builtin_amdgcn_s_setprio(1);
#pragma unroll
    for (int jj = 0; jj < 4; jj++)
#pragma unroll
      for (int n = 0; n < 2; n++) {
        acc[jj][n] = mfma16(a_lo[jj][0], b_lo[n][0], acc[jj][n]);
        acc[jj][n] = mfma16(a_lo[jj][1], b_lo[n][1], acc[jj][n]);
      }
    __builtin_amdgcn_s_setprio(0);
    // phase 1: read b_hi(cur); stage B-h0(nxt); drain A-h1(cur)
#pragma unroll
    for (int n = 0; n < 2; n++) { b_hi[n][0] = ldB(cur, 2 + n, 0); b_hi[n][1] = ldB(cur, 2 + n, 1); }
    if (hn) stageB(nxt, ktn, 0);
    if (hn) asm volatile("s_waitcnt vmcnt(4)" ::: "memory");
    else    asm volatile("s_waitcnt vmcnt(0)" ::: "memory");
    __builtin_amdgcn_s_barrier();
    __builtin_amdgcn_sched_barrier(0);
    __builtin_amdgcn_s_setprio(1);
#pragma unroll
    for (int jj = 0; jj < 4; jj++)
#pragma unroll
      for (int n = 0; n < 2; n++) {
        acc[jj][2 + n] = mfma16(a_lo[jj][0], b_hi[n][0], acc[jj][2 + n]);
        acc[jj][2 + n] = mfma16(a_lo[jj][1], b_hi[n][1], acc[jj][2 + n]);
      }
    __builtin_amdgcn_s_setprio(0);
    // phase 2: read a_hi(cur); stage B-h1(nxt); no wait
#pragma unroll
    for (int jj = 0; jj < 4; jj++) { a_hi[jj][0] = ldA(cur, 4 + jj, 0); a_hi[jj][1] = ldA(cur, 4 + jj, 1); }
    if (hn) stageB(nxt, ktn, 1);
    __builtin_amdgcn_s_barrier();
    __builtin_amdgcn_sched_barrier(0);
    __builtin_amdgcn_s_setprio(1);
#pragma unroll
    for (int jj = 0; jj < 4; jj++)
#pragma unroll
      for (int n = 0; n < 2; n++) {
        acc[4 + jj][n] = mfma16(a_hi[jj][0], b_lo[n][0], acc[4 + jj][n]);
        acc[4 + jj][n] = mfma16(a_hi[jj][1], b_lo[n][1], acc[4 + jj][n]);
      }
    __builtin_amdgcn_s_setprio(0);
    // phase 3: no reads; stage A-h1(nxt); drain A-h0,B-h0(nxt)
    if (hn) stageA(nxt, ktn, 1);
    if (hn) asm volatile("s_waitcnt vmcnt(4)" ::: "memory");
    __builtin_amdgcn_s_barrier();
    __builtin_amdgcn_sched_barrier(0);
    __builtin_amdgcn_s_setprio(1);
#pragma unroll
    for (int jj = 0; jj < 4; jj++)
#pragma unroll
      for (int n = 0; n < 2; n++) {
        acc[4 + jj][2 + n] = mfma16(a_hi[jj][0], b_hi[n][0], acc[4 + jj][2 + n]);
        acc[4 + jj][2 + n] = mfma16(a_hi[jj][1], b_hi[n][1], acc[4 + jj][2 + n]);
      }
    __builtin_amdgcn_s_setprio(0);
  }

#pragma unroll
  for (int jj = 0; jj < 8; jj++)
#pragma unroll
    for (int n = 0; n < 4; n++) {
      const int col = n0 + (4 * n + wn) * 16 + i;
      const float bv = bias[col];
#pragma unroll
      for (int r = 0; r < 4; r++) {
        const int row = m0 + (2 * jj + wm) * 16 + g * 4 + r;
        epilogue_store<EPI>(acc[jj][n][r] + bv, row, col, Nn, res, outf, outb, oq, ok, ov);
      }
    }
}

// ---------------- 128x256 2-phase/K-tile GEMM (QKV / proj / FC2) ----------------
// v4: same treatment — blanket lgkmcnt(0) removed, B-first read order.
template <int EPI>
__global__ __launch_bounds__(512, 2) void gemm128(
    const unsigned short* __restrict__ A, const unsigned short* __restrict__ Bt,
    const float* __restrict__ bias, const float* __restrict__ res,
    float* __restrict__ outf, unsigned short* __restrict__ outb,
    unsigned short* __restrict__ oq, unsigned short* __restrict__ ok,
    unsigned short* __restrict__ ov, int Nn, int Kk, int nbn) {
  __shared__ unsigned short As[2][128 * 64];   // 32 KiB
  __shared__ unsigned short Bs[2][256 * 64];   // 64 KiB
  const int tid = threadIdx.x;
  const int lane = tid & 63, wid = tid >> 6;
  const int i = lane & 15, g = lane >> 4;
  const int wm = wid >> 2, wn = wid & 3;
  const int nwg = gridDim.x;
  const int sid = (blockIdx.x & 7) * (nwg >> 3) + (blockIdx.x >> 3);
  const int m0 = (sid / nbn) * 128, n0 = (sid % nbn) * 256;

  auto stageA = [&](int bf, int kt) {
#pragma unroll
    for (int c = 0; c < 2; c++) {
      const int cb = c * 512 + wid * 64;
      const int ci = cb + lane;
      const int row = ci >> 3;
      const int kc = (ci & 7) ^ (row & 7);
      gload_lds16(A + (size_t)(m0 + row) * Kk + kt + kc * 8, &As[bf][(size_t)cb * 8]);
    }
  };
  auto stageB = [&](int bf, int kt, int h) {
#pragma unroll
    for (int c = 0; c < 2; c++) {
      const int cb = h * 1024 + c * 512 + wid * 64;
      const int ci = cb + lane;
      const int row = ci >> 3;
      const int kc = (ci & 7) ^ (row & 7);
      gload_lds16(Bt + (size_t)(n0 + row) * Kk + kt + kc * 8, &Bs[bf][(size_t)cb * 8]);
    }
  };
  auto ldA = [&](int bf, int jj, int ks) -> bf16x8 {
    const int row = (2 * jj + wm) * 16 + i;
    return *(const bf16x8*)((const char*)&As[bf][0] + row * 128 + ((((ks << 2) + g) ^ (i & 7)) << 4));
  };
  auto ldB = [&](int bf, int n, int ks) -> bf16x8 {
    const int row = (4 * n + wn) * 16 + i;
    return *(const bf16x8*)((const char*)&Bs[bf][0] + row * 128 + ((((ks << 2) + g) ^ (i & 7)) << 4));
  };

  f32x4 acc[4][4] = {};
  const int NT = Kk >> 6;

  stageA(0, 0);
  stageB(0, 0, 0);
  stageB(0, 0, 1);
  asm volatile("s_waitcnt vmcnt(2)" ::: "memory");
  __builtin_amdgcn_s_barrier();
  __builtin_amdgcn_sched_barrier(0);

  bf16x8 af[4][2], b_lo[2][2], b_hi[2][2];
  for (int t = 0; t < NT; ++t) {
    const int cur = t & 1, nxt = cur ^ 1;
    const int ktn = (t + 1) << 6;
    const bool hn = (t + 1) < NT;
    // ---- PH0: read b_lo,af(cur); stage A+B-h0(nxt); drain B-h1(cur)
#pragma unroll
    for (int n = 0; n < 2; n++) { b_lo[n][0] = ldB(cur, n, 0); b_lo[n][1] = ldB(cur, n, 1); }
#pragma unroll
    for (int jj = 0; jj < 4; jj++) { af[jj][0] = ldA(cur, jj, 0); af[jj][1] = ldA(cur, jj, 1); }
    if (hn) { stageA(nxt, ktn); stageB(nxt, ktn, 0); }
    if (hn) asm volatile("s_waitcnt vmcnt(4)" ::: "memory");
    else    asm volatile("s_waitcnt vmcnt(0)" ::: "memory");
    __builtin_amdgcn_s_barrier();
    __builtin_amdgcn_sched_barrier(0);
    __builtin_amdgcn_s_setprio(1);
#pragma unroll
    for (int jj = 0; jj < 4; jj++)
#pragma unroll
      for (int n = 0; n < 2; n++) {
        acc[jj][n] = mfma16(af[jj][0], b_lo[n][0], acc[jj][n]);
        acc[jj][n] = mfma16(af[jj][1], b_lo[n][1], acc[jj][n]);
      }
    __builtin_amdgcn_s_setprio(0);
    // ---- PH1: read b_hi(cur); stage B-h1(nxt); drain A,B-h0(nxt)
#pragma unroll
    for (int n = 0; n < 2; n++) { b_hi[n][0] = ldB(cur, 2 + n, 0); b_hi[n][1] = ldB(cur, 2 + n, 1); }
    if (hn) stageB(nxt, ktn, 1);
    if (hn) asm volatile("s_waitcnt vmcnt(2)" ::: "memory");
    __builtin_amdgcn_s_barrier();
    __builtin_amdgcn_sched_barrier(0);
    __builtin_amdgcn_s_setprio(1);
#pragma unroll
    for (int jj = 0; jj < 4; jj++)
#pragma unroll
      for (int n = 0; n < 2; n++) {
        acc[jj][2 + n] = mfma16(af[jj][0], b_hi[n][0], acc[jj][2 + n]);
        acc[jj][2 + n] = mfma16(af[jj][1], b_hi[n][1], acc[jj][2 + n]);
      }
    __builtin_amdgcn_s_setprio(0);
  }

#pragma unroll
  for (int jj = 0; jj < 4; jj++)
#pragma unroll
    for (int n = 0; n < 4; n++) {
      const int col = n0 + (4 * n + wn) * 16 + i;
      const float bv = bias[col];
#pragma unroll
      for (int r = 0; r < 4; r++) {
        const int row = m0 + (2 * jj + wm) * 16 + g * 4 + r;
        epilogue_store<EPI>(acc[jj][n][r] + bv, row, col, Nn, res, outf, outb, oq, ok, ov);
      }
    }
}

// ---------------- causal flash attention (paired q-tiles, swapped QK^T) ----------------
// q,k: (BH, T, 128) bf16; vt: (BH, 128, T) bf16; y: (B, T, C) bf16
__global__ __launch_bounds__(256) void attn_kernel(
    const unsigned short* __restrict__ q, const unsigned short* __restrict__ k,
    const unsigned short* __restrict__ vt, unsigned short* __restrict__ y) {
  __shared__ unsigned short Ks[64 * 128];   // swizzled [kv][hs]
  __shared__ unsigned short Vs[128 * 64];   // swizzled [d][kv]
  __shared__ unsigned short Ps[4][16 * 64]; // per-wave swizzled [q=i][kv]
  const int tid = threadIdx.x, lane = tid & 63, w = tid >> 6;
  const int i = lane & 15, g = lane >> 4;
  const int p = blockIdx.x, bh = blockIdx.y;
  const int q0A = p * 64, q0B = (31 - p) * 64;
  const int tB = 31 - p;
  const size_t hb = (size_t)bh * (2048 * 128);
  const float sc2 = 0.08838834764831845f * 1.44269504088896341f;

  bf16x8 qfA[4], qfB[4];
  {
    const int qra = q0A + w * 16 + i, qrb = q0B + w * 16 + i;
#pragma unroll
    for (int kc = 0; kc < 4; kc++) {
      qfA[kc] = *(const bf16x8*)(q + hb + (size_t)qra * 128 + kc * 32 + g * 8);
      qfB[kc] = *(const bf16x8*)(q + hb + (size_t)qrb * 128 + kc * 32 + g * 8);
    }
  }
  f32x4 oA[8] = {}, oB[8] = {};
  float mA = -__builtin_inff(), lA = 0.f, mB = -__builtin_inff(), lB = 0.f;

  auto proc = [&](const bf16x8 (&qf)[4], f32x4 (&oacc)[8], float& mrun, float& lrun,
                  bool diag) {
    f32x4 st[4];
#pragma unroll
    for (int ct = 0; ct < 4; ct++) {
      f32x4 a = {};
      const int kvr = ct * 16 + i;
#pragma unroll
      for (int kc = 0; kc < 4; kc++) {
        bf16x8 kf = *(const bf16x8*)((char*)Ks + kvr * 256 + (((kc * 4 + g) ^ (i & 7)) << 4));
        a = mfma16(kf, qf[kc], a);
      }
      st[ct] = a;
    }
    float tm = -__builtin_inff();
    const int ql = w * 16 + i;
#pragma unroll
    for (int ct = 0; ct < 4; ct++)
#pragma unroll
      for (int r = 0; r < 4; r++) {
        float v = st[ct][r] * sc2;
        if (diag) {
          const int kvl = ct * 16 + g * 4 + r;
          if (kvl > ql) v = -__builtin_inff();
        }
        st[ct][r] = v;
        tm = fmaxf(tm, v);
      }
    tm = fmaxf(tm, __shfl_xor(tm, 16, 64));
    tm = fmaxf(tm, __shfl_xor(tm, 32, 64));
    if (!__all(tm - mrun <= 8.f)) {
      const float mnew = fmaxf(mrun, tm);
      const float al = exp2fast(mrun - mnew);
      float ar[4];
#pragma unroll
      for (int r = 0; r < 4; r++) ar[r] = __shfl(al, g * 4 + r, 64);
#pragma unroll
      for (int dt = 0; dt < 8; dt++)
#pragma unroll
        for (int r = 0; r < 4; r++) oacc[dt][r] *= ar[r];
      lrun *= al;
      mrun = mnew;
    }
    float ps = 0.f;
#pragma unroll
    for (int ct = 0; ct < 4; ct++)
#pragma unroll
      for (int r = 0; r < 4; r++) {
        const float pv = exp2fast(st[ct][r] - mrun);
        st[ct][r] = pv;
        ps += pv;
      }
    ps += __shfl_xor(ps, 16, 64);
    ps += __shfl_xor(ps, 32, 64);
    lrun += ps;
#pragma unroll
    for (int ct = 0; ct < 4; ct++) {
      unsigned w0, w1;
      asm("v_cvt_pk_bf16_f32 %0, %1, %2" : "=v"(w0) : "v"(st[ct][0]), "v"(st[ct][1]));
      asm("v_cvt_pk_bf16_f32 %0, %1, %2" : "=v"(w1) : "v"(st[ct][2]), "v"(st[ct][3]));
      char* pb = (char*)&Ps[w][0] + i * 128 +
                 ((((2 * ct + (g >> 1)) ^ (i & 7)) << 4) + (g & 1) * 8);
      *(uint2*)pb = make_uint2(w0, w1);
    }
    bf16x8 pf[2];
#pragma unroll
    for (int kvc = 0; kvc < 2; kvc++)
      pf[kvc] = *(const bf16x8*)((char*)&Ps[w][0] + i * 128 + (((kvc * 4 + g) ^ (i & 7)) << 4));
#pragma unroll
    for (int dt = 0; dt < 8; dt++) {
      const int dr = dt * 16 + i;
#pragma unroll
      for (int kvc = 0; kvc < 2; kvc++) {
        bf16x8 vf = *(const bf16x8*)((char*)Vs + dr * 128 + (((kvc * 4 + g) ^ (dr & 7)) << 4));
        oacc[dt] = mfma16(pf[kvc], vf, oacc[dt]);
      }
    }
  };

  for (int t = 0; t <= tB; ++t) {
    const int j0 = t * 64;
    __syncthreads();
#pragma unroll
    for (int it = 0; it < 4; it++) {
      const int ci = it * 256 + tid;
      const int kv = ci >> 4, ccl = ci & 15;
      gload_lds16(k + hb + (size_t)(j0 + kv) * 128 + ((ccl ^ (kv & 7)) << 3),
                  (char*)Ks + (size_t)(it * 256 + w * 64) * 16);
      const int dd = ci >> 3, c2l = ci & 7;
      gload_lds16(vt + hb + (size_t)dd * 2048 + j0 + ((c2l ^ (dd & 7)) << 3),
                  (char*)Vs + (size_t)(it * 256 + w * 64) * 16);
    }
    __syncthreads();
    if (t <= p) proc(qfA, oA, mA, lA, t == p);
    proc(qfB, oB, mB, lB, t == tB);
  }

  const int bb = bh >> 4, hh = bh & 15;
  auto finish = [&](const f32x4 (&oacc)[8], float lrun, int q0s) {
    const float inv_i = 1.f / lrun;
    float ir[4];
#pragma unroll
    for (int r = 0; r < 4; r++) ir[r] = __shfl(inv_i, g * 4 + r, 64);
#pragma unroll
    for (int r = 0; r < 4; r++) {
      const int row = q0s + w * 16 + g * 4 + r;
#pragma unroll
      for (int dt = 0; dt < 8; dt++) {
        const int d = dt * 16 + i;
        y[((size_t)(bb * 2048 + row)) * 2048 + hh * 128 + d] = f2bf(oacc[dt][r] * ir[r]);
      }
    }
  };
  finish(oA, lA, q0A);
  finish(oB, lB, q0B);
}

// ---------------- launcher ----------------
extern "C" void kernel_launch(void* const* d_in, const int* in_sizes, int n_in,
                              void* d_out, int out_size, void* d_ws, size_t ws_size,
                              hipStream_t stream) {
  const float* x      = (const float*)d_in[0];
  const float* ln1_w  = (const float*)d_in[1];
  const float* ln1_b  = (const float*)d_in[2];
  const float* w_qkv  = (const float*)d_in[3];
  const float* b_qkv  = (const float*)d_in[4];
  const float* w_proj = (const float*)d_in[5];
  const float* b_proj = (const float*)d_in[6];
  const float* ln2_w  = (const float*)d_in[7];
  const float* ln2_b  = (const float*)d_in[8];
  const float* w_fc   = (const float*)d_in[9];
  const float* b_fc   = (const float*)d_in[10];
  const float* w_fc2  = (const float*)d_in[11];
  const float* b_fc2  = (const float*)d_in[12];

  char* ws = (char*)d_ws;
  unsigned short* wt_qkv  = (unsigned short*)(ws + 0);          // 25165824 B
  unsigned short* wt_proj = (unsigned short*)(ws + 25165824);   // 8388608
  unsigned short* qb      = (unsigned short*)(ws + 33554432);   // 16777216
  unsigned short* kb      = (unsigned short*)(ws + 50331648);   // 16777216
  unsigned short* wt_fc   = (unsigned short*)(ws + 67108864);   // 33554432
  unsigned short* wt_fc2  = (unsigned short*)(ws + 100663296);  // 33554432
  unsigned short* hb      = (unsigned short*)(ws + 134217728);  // 16777216 (h1/h2)
  unsigned short* vtb     = (unsigned short*)(ws + 150994944);  // 16777216
  unsigned short* yb      = (unsigned short*)(ws + 167772160);  // 16777216 (vb then y)
  float*          x1      = (float*)(ws + 184549376);           // 33554432 (ends 218103808)
  unsigned short* hfc     = (unsigned short*)(ws + 0);          // 67108864, aliases dead wt_qkv/wt_proj/qb/kb
  float* outp = (float*)d_out;

  dim3 tb(32, 8);
  transpose_to_bf16<<<dim3(6144 / 32, 2048 / 32), tb, 0, stream>>>(w_qkv, wt_qkv, 2048, 6144);
  transpose_to_bf16<<<dim3(2048 / 32, 2048 / 32), tb, 0, stream>>>(w_proj, wt_proj, 2048, 2048);
  transpose_to_bf16<<<dim3(8192 / 32, 2048 / 32), tb, 0, stream>>>(w_fc, wt_fc, 2048, 8192);
  transpose_to_bf16<<<dim3(2048 / 32, 8192 / 32), tb, 0, stream>>>(w_fc2, wt_fc2, 8192, 2048);

  ln_kernel<<<4096, 256, 0, stream>>>(x, ln1_w, ln1_b, hb);

  // qkv: 128x256 tiles -> 32x24 = 768 blocks (3 clean rounds)
  gemm128<0><<<768, 512, 0, stream>>>(
      hb, wt_qkv, b_qkv, nullptr, nullptr, nullptr, qb, kb, yb, 6144, 2048, 24);
  transpose_v<<<dim3(2048 / 32, 128 / 32, 32), tb, 0, stream>>>(yb, vtb);

  // paired causal q-tiles: 16 pairs x 32 bh = 512 blocks, uniform work
  attn_kernel<<<dim3(16, 32), 256, 0, stream>>>(qb, kb, vtb, yb);

  // proj + residual -> x1 (f32): 32x8 = 256 blocks (1 clean round)
  gemm128<2><<<256, 512, 0, stream>>>(
      yb, wt_proj, b_proj, x, x1, nullptr, nullptr, nullptr, nullptr, 2048, 2048, 8);

  ln_kernel<<<4096, 256, 0, stream>>>(x1, ln2_w, ln2_b, hb);

  // fc + GELU -> hfc (bf16): 256x256 tiles, 512 blocks (2 clean rounds)
  gemm256<1><<<512, 512, 0, stream>>>(
      hb, wt_fc, b_fc, nullptr, nullptr, hfc, nullptr, nullptr, nullptr, 8192, 2048, 32);

  // fc2 + residual -> out (f32): 32x8 = 256 blocks (1 clean round)
  gemm128<2><<<256, 512, 0, stream>>>(
      hfc, wt_fc2, b_fc2, x1, outp, nullptr, nullptr, nullptr, nullptr, 2048, 8192, 8);
}

// Round 4
// 655.732 us; speedup vs baseline: 1.1108x; 1.0136x over previous
//
#include <hip/hip_runtime.h>
#include <hip/hip_bf16.h>
#include <cstdint>
#include <cstddef>

typedef __attribute__((ext_vector_type(8))) short bf16x8;
typedef __attribute__((ext_vector_type(4))) float f32x4;

#define DEVI __device__ __forceinline__

DEVI unsigned short f2bf(float f) {
  union { float f; unsigned u; } x; x.f = f;
  unsigned r = x.u + 0x7fffu + ((x.u >> 16) & 1u);
  return (unsigned short)(r >> 16);
}

DEVI float exp2fast(float x) {
#if __has_builtin(__builtin_amdgcn_exp2f)
  return __builtin_amdgcn_exp2f(x);
#else
  return exp2f(x);
#endif
}

DEVI void gload_lds16(const void* g, void* l) {
  __builtin_amdgcn_global_load_lds((const __attribute__((address_space(1))) void*)g,
                                   (__attribute__((address_space(3))) void*)l, 16, 0, 0);
}

DEVI f32x4 mfma16(bf16x8 a, bf16x8 b, f32x4 c) {
  return __builtin_amdgcn_mfma_f32_16x16x32_bf16(a, b, c, 0, 0, 0);
}

// ---------------- weight transpose fp32 (K,N) -> bf16 (N,K) ----------------
__global__ __launch_bounds__(256) void transpose_to_bf16(
    const float* __restrict__ w, unsigned short* __restrict__ wt, int K, int N) {
  __shared__ float tile[32][33];
  const int n0 = blockIdx.x * 32, k0 = blockIdx.y * 32;
  const int tx = threadIdx.x, ty = threadIdx.y;
#pragma unroll
  for (int i = 0; i < 4; i++)
    tile[ty + i * 8][tx] = w[(size_t)(k0 + ty + i * 8) * N + n0 + tx];
  __syncthreads();
#pragma unroll
  for (int i = 0; i < 4; i++)
    wt[(size_t)(n0 + ty + i * 8) * K + k0 + tx] = f2bf(tile[tx][ty + i * 8]);
}

// ---------------- bf16 per-head transpose (BH,T,HS) -> (BH,HS,T) ----------------
__global__ __launch_bounds__(256) void transpose_v(
    const unsigned short* __restrict__ in, unsigned short* __restrict__ out) {
  __shared__ unsigned short tile[32][33];
  const int bh = blockIdx.z;
  const unsigned short* inp = in + (size_t)bh * 2048 * 128;
  unsigned short* op = out + (size_t)bh * 2048 * 128;
  const int t0 = blockIdx.x * 32, d0 = blockIdx.y * 32;
  const int tx = threadIdx.x, ty = threadIdx.y;
#pragma unroll
  for (int i = 0; i < 4; i++)
    tile[ty + i * 8][tx] = inp[(size_t)(t0 + ty + i * 8) * 128 + d0 + tx];
  __syncthreads();
#pragma unroll
  for (int i = 0; i < 4; i++)
    op[(size_t)(d0 + ty + i * 8) * 2048 + t0 + tx] = tile[tx][ty + i * 8];
}

// ---------------- LayerNorm: f32 row(2048) -> bf16 ----------------
__global__ __launch_bounds__(256) void ln_kernel(
    const float* __restrict__ x, const float* __restrict__ gw,
    const float* __restrict__ gb, unsigned short* __restrict__ out) {
  __shared__ float red[8];
  const int row = blockIdx.x, tid = threadIdx.x;
  const float* xr = x + (size_t)row * 2048;
  f32x4 a = *((const f32x4*)xr + tid * 2);
  f32x4 b = *((const f32x4*)xr + tid * 2 + 1);
  float s = a[0] + a[1] + a[2] + a[3] + b[0] + b[1] + b[2] + b[3];
#pragma unroll
  for (int m = 32; m >= 1; m >>= 1) s += __shfl_xor(s, m, 64);
  if ((tid & 63) == 0) red[tid >> 6] = s;
  __syncthreads();
  const float mu = (red[0] + red[1] + red[2] + red[3]) * (1.f / 2048.f);
  float d[8]; float ss = 0.f;
#pragma unroll
  for (int j = 0; j < 8; j++) {
    float v = ((j < 4) ? a[j] : b[j - 4]) - mu;
    d[j] = v; ss += v * v;
  }
#pragma unroll
  for (int m = 32; m >= 1; m >>= 1) ss += __shfl_xor(ss, m, 64);
  __syncthreads();
  if ((tid & 63) == 0) red[4 + (tid >> 6)] = ss;
  __syncthreads();
  const float var = (red[4] + red[5] + red[6] + red[7]) * (1.f / 2048.f);
  const float rstd = rsqrtf(var + 1e-5f);
  f32x4 w0 = *((const f32x4*)gw + tid * 2), w1 = *((const f32x4*)gw + tid * 2 + 1);
  f32x4 b0 = *((const f32x4*)gb + tid * 2), b1 = *((const f32x4*)gb + tid * 2 + 1);
  union { bf16x8 v; unsigned short u[8]; } o;
#pragma unroll
  for (int j = 0; j < 8; j++) {
    float wv = (j < 4) ? w0[j] : w1[j - 4];
    float bv = (j < 4) ? b0[j] : b1[j - 4];
    o.u[j] = f2bf(d[j] * rstd * wv + bv);
  }
  *(bf16x8*)(out + (size_t)row * 2048 + tid * 8) = o.v;
}

// =====================================================================
// Shared epilogue: C[row,col] with row = m0+(2jj+wm)*16+g*4+r, col = n0+(4n+wn)*16+i
// EPI 0: QKV scatter to q/k/v head layout bf16; EPI 1: GELU -> bf16; EPI 2: +res -> f32
template <int EPI>
DEVI void epilogue_store(float v, int row, int col, int Nn,
                         const float* __restrict__ res, float* __restrict__ outf,
                         unsigned short* __restrict__ outb, unsigned short* __restrict__ oq,
                         unsigned short* __restrict__ ok, unsigned short* __restrict__ ov) {
  if constexpr (EPI == 0) {
    const int which = col >> 11, cc = col & 2047;
    const int hh = cc >> 7, hs = cc & 127;
    const int bb = row >> 11, tt = row & 2047;
    const size_t bh = (size_t)(bb * 16 + hh);
    const unsigned short bits = f2bf(v);
    if (which == 0) oq[(bh * 2048 + tt) * 128 + hs] = bits;
    else if (which == 1) ok[(bh * 2048 + tt) * 128 + hs] = bits;
    else ov[(bh * 2048 + tt) * 128 + hs] = bits;
  } else if constexpr (EPI == 1) {
    const float ge = 0.5f * v * (1.0f + erff(v * 0.70710678118654752f));
    outb[(size_t)row * Nn + col] = f2bf(ge);
  } else {
    outf[(size_t)row * Nn + col] = v + res[(size_t)row * Nn + col];
  }
}

// ---------------- 256x256 2-phase/K-tile GEMM (used for FC) ----------------
// v5: phases merged 4 -> 2 per K-tile (per-phase overhead ~650cy was the
// dominant residual; barriers/K-tile 4->2, vmcnt 3->2). Same registers (all
// 24 fragments were already live). Schedule per K-tile:
//  ph0: read b_lo,a_lo(cur); stage A-h0+B-h0(nxt); vmcnt(4) [drains
//       B-h1,A-h1(cur) staged 1 phase ago]; BAR; 16 MFMA q00.
//  ph1: read b_hi,a_hi(cur); stage B-h1+A-h1(nxt); vmcnt(4) [drains
//       A-h0,B-h0(nxt) for t+1 ph0]; BAR; 48 MFMA q01->q10->q11
//       (q01 needs only b_hi -> lgkm staircase friendly).
// Hazards: every region vmcnt-drained one barrier before its ds_read; every
// overwrite one barrier after all consuming MFMAs (reads land in regs before
// the MFMAs preceding that barrier).
template <int EPI>
__global__ __launch_bounds__(512, 2) void gemm256(
    const unsigned short* __restrict__ A, const unsigned short* __restrict__ Bt,
    const float* __restrict__ bias, const float* __restrict__ res,
    float* __restrict__ outf, unsigned short* __restrict__ outb,
    unsigned short* __restrict__ oq, unsigned short* __restrict__ ok,
    unsigned short* __restrict__ ov, int Nn, int Kk, int nbn) {
  __shared__ unsigned short As[2][256 * 64];
  __shared__ unsigned short Bs[2][256 * 64];
  const int tid = threadIdx.x;
  const int lane = tid & 63, wid = tid >> 6;
  const int i = lane & 15, g = lane >> 4;
  const int wm = wid >> 2, wn = wid & 3;
  const int nwg = gridDim.x;
  const int sid = (blockIdx.x & 7) * (nwg >> 3) + (blockIdx.x >> 3);
  const int m0 = (sid / nbn) * 256, n0 = (sid % nbn) * 256;

  auto stageA = [&](int bf, int kt, int h) {
#pragma unroll
    for (int c = 0; c < 2; c++) {
      const int cb = h * 1024 + c * 512 + wid * 64;
      const int ci = cb + lane;
      const int row = ci >> 3;
      const int kc = (ci & 7) ^ (row & 7);
      gload_lds16(A + (size_t)(m0 + row) * Kk + kt + kc * 8, &As[bf][(size_t)cb * 8]);
    }
  };
  auto stageB = [&](int bf, int kt, int h) {
#pragma unroll
    for (int c = 0; c < 2; c++) {
      const int cb = h * 1024 + c * 512 + wid * 64;
      const int ci = cb + lane;
      const int row = ci >> 3;
      const int kc = (ci & 7) ^ (row & 7);
      gload_lds16(Bt + (size_t)(n0 + row) * Kk + kt + kc * 8, &Bs[bf][(size_t)cb * 8]);
    }
  };
  auto ldA = [&](int bf, int jj, int ks) -> bf16x8 {
    const int row = (2 * jj + wm) * 16 + i;
    return *(const bf16x8*)((const char*)&As[bf][0] + row * 128 + ((((ks << 2) + g) ^ (i & 7)) << 4));
  };
  auto ldB = [&](int bf, int n, int ks) -> bf16x8 {
    const int row = (4 * n + wn) * 16 + i;
    return *(const bf16x8*)((const char*)&Bs[bf][0] + row * 128 + ((((ks << 2) + g) ^ (i & 7)) << 4));
  };

  f32x4 acc[8][4] = {};
  const int NT = Kk >> 6;

  // prologue: stage tile 0 fully; drain h0 halves -> identical steady state
  stageA(0, 0, 0);
  stageB(0, 0, 0);
  stageB(0, 0, 1);
  stageA(0, 0, 1);
  asm volatile("s_waitcnt vmcnt(4)" ::: "memory");
  __builtin_amdgcn_s_barrier();
  __builtin_amdgcn_sched_barrier(0);

  bf16x8 a_lo[4][2], a_hi[4][2], b_lo[2][2], b_hi[2][2];
  for (int t = 0; t < NT; ++t) {
    const int cur = t & 1, nxt = cur ^ 1;
    const int ktn = (t + 1) << 6;
    const bool hn = (t + 1) < NT;
    // ---- ph0: read b_lo,a_lo(cur); stage A-h0+B-h0(nxt); 16 MFMA q00
#pragma unroll
    for (int n = 0; n < 2; n++) { b_lo[n][0] = ldB(cur, n, 0); b_lo[n][1] = ldB(cur, n, 1); }
#pragma unroll
    for (int jj = 0; jj < 4; jj++) { a_lo[jj][0] = ldA(cur, jj, 0); a_lo[jj][1] = ldA(cur, jj, 1); }
    if (hn) { stageA(nxt, ktn, 0); stageB(nxt, ktn, 0); }
    if (hn) asm volatile("s_waitcnt vmcnt(4)" ::: "memory");
    else    asm volatile("s_waitcnt vmcnt(0)" ::: "memory");
    __builtin_amdgcn_s_barrier();
    __builtin_amdgcn_sched_barrier(0);
    __builtin_amdgcn_s_setprio(1);
#pragma unroll
    for (int jj = 0; jj < 4; jj++)
#pragma unroll
      for (int n = 0; n < 2; n++) {
        acc[jj][n] = mfma16(a_lo[jj][0], b_lo[n][0], acc[jj][n]);
        acc[jj][n] = mfma16(a_lo[jj][1], b_lo[n][1], acc[jj][n]);
      }
    __builtin_amdgcn_s_setprio(0);
    // ---- ph1: read b_hi,a_hi(cur); stage B-h1+A-h1(nxt); 48 MFMA q01,q10,q11
#pragma unroll
    for (int n = 0; n < 2; n++) { b_hi[n][0] = ldB(cur, 2 + n, 0); b_hi[n][1] = ldB(cur, 2 + n, 1); }
#pragma unroll
    for (int jj = 0; jj < 4; jj++) { a_hi[jj][0] = ldA(cur, 4 + jj, 0); a_hi[jj][1] = ldA(cur, 4 + jj, 1); }
    if (hn) { stageB(nxt, ktn, 1); stageA(nxt, ktn, 1); }
    if (hn) asm volatile("s_waitcnt vmcnt(4)" ::: "memory");
    __builtin_amdgcn_s_barrier();
    __builtin_amdgcn_sched_barrier(0);
    __builtin_amdgcn_s_setprio(1);
    // q01: a_lo x b_hi (needs only b_hi reads)
#pragma unroll
    for (int jj = 0; jj < 4; jj++)
#pragma unroll
      for (int n = 0; n < 2; n++) {
        acc[jj][2 + n] = mfma16(a_lo[jj][0], b_hi[n][0], acc[jj][2 + n]);
        acc[jj][2 + n] = mfma16(a_lo[jj][1], b_hi[n][1], acc[jj][2 + n]);
      }
    // q10: a_hi x b_lo
#pragma unroll
    for (int jj = 0; jj < 4; jj++)
#pragma unroll
      for (int n = 0; n < 2; n++) {
        acc[4 + jj][n] = mfma16(a_hi[jj][0], b_lo[n][0], acc[4 + jj][n]);
        acc[4 + jj][n] = mfma16(a_hi[jj][1], b_lo[n][1], acc[4 + jj][n]);
      }
    // q11: a_hi x b_hi
#pragma unroll
    for (int jj = 0; jj < 4; jj++)
#pragma unroll
      for (int n = 0; n < 2; n++) {
        acc[4 + jj][2 + n] = mfma16(a_hi[jj][0], b_hi[n][0], acc[4 + jj][2 + n]);
        acc[4 + jj][2 + n] = mfma16(a_hi[jj][1], b_hi[n][1], acc[4 + jj][2 + n]);
      }
    __builtin_amdgcn_s_setprio(0);
  }

#pragma unroll
  for (int jj = 0; jj < 8; jj++)
#pragma unroll
    for (int n = 0; n < 4; n++) {
      const int col = n0 + (4 * n + wn) * 16 + i;
      const float bv = bias[col];
#pragma unroll
      for (int r = 0; r < 4; r++) {
        const int row = m0 + (2 * jj + wm) * 16 + g * 4 + r;
        epilogue_store<EPI>(acc[jj][n][r] + bv, row, col, Nn, res, outf, outb, oq, ok, ov);
      }
    }
}

// ---------------- 128x256 2-phase/K-tile GEMM (QKV / proj / FC2) ----------------
// v4 state kept (single barrier per phase, B-first read order, no blanket lgkm).
template <int EPI>
__global__ __launch_bounds__(512, 2) void gemm128(
    const unsigned short* __restrict__ A, const unsigned short* __restrict__ Bt,
    const float* __restrict__ bias, const float* __restrict__ res,
    float* __restrict__ outf, unsigned short* __restrict__ outb,
    unsigned short* __restrict__ oq, unsigned short* __restrict__ ok,
    unsigned short* __restrict__ ov, int Nn, int Kk, int nbn) {
  __shared__ unsigned short As[2][128 * 64];   // 32 KiB
  __shared__ unsigned short Bs[2][256 * 64];   // 64 KiB
  const int tid = threadIdx.x;
  const int lane = tid & 63, wid = tid >> 6;
  const int i = lane & 15, g = lane >> 4;
  const int wm = wid >> 2, wn = wid & 3;
  const int nwg = gridDim.x;
  const int sid = (blockIdx.x & 7) * (nwg >> 3) + (blockIdx.x >> 3);
  const int m0 = (sid / nbn) * 128, n0 = (sid % nbn) * 256;

  auto stageA = [&](int bf, int kt) {
#pragma unroll
    for (int c = 0; c < 2; c++) {
      const int cb = c * 512 + wid * 64;
      const int ci = cb + lane;
      const int row = ci >> 3;
      const int kc = (ci & 7) ^ (row & 7);
      gload_lds16(A + (size_t)(m0 + row) * Kk + kt + kc * 8, &As[bf][(size_t)cb * 8]);
    }
  };
  auto stageB = [&](int bf, int kt, int h) {
#pragma unroll
    for (int c = 0; c < 2; c++) {
      const int cb = h * 1024 + c * 512 + wid * 64;
      const int ci = cb + lane;
      const int row = ci >> 3;
      const int kc = (ci & 7) ^ (row & 7);
      gload_lds16(Bt + (size_t)(n0 + row) * Kk + kt + kc * 8, &Bs[bf][(size_t)cb * 8]);
    }
  };
  auto ldA = [&](int bf, int jj, int ks) -> bf16x8 {
    const int row = (2 * jj + wm) * 16 + i;
    return *(const bf16x8*)((const char*)&As[bf][0] + row * 128 + ((((ks << 2) + g) ^ (i & 7)) << 4));
  };
  auto ldB = [&](int bf, int n, int ks) -> bf16x8 {
    const int row = (4 * n + wn) * 16 + i;
    return *(const bf16x8*)((const char*)&Bs[bf][0] + row * 128 + ((((ks << 2) + g) ^ (i & 7)) << 4));
  };

  f32x4 acc[4][4] = {};
  const int NT = Kk >> 6;

  stageA(0, 0);
  stageB(0, 0, 0);
  stageB(0, 0, 1);
  asm volatile("s_waitcnt vmcnt(2)" ::: "memory");
  __builtin_amdgcn_s_barrier();
  __builtin_amdgcn_sched_barrier(0);

  bf16x8 af[4][2], b_lo[2][2], b_hi[2][2];
  for (int t = 0; t < NT; ++t) {
    const int cur = t & 1, nxt = cur ^ 1;
    const int ktn = (t + 1) << 6;
    const bool hn = (t + 1) < NT;
    // ---- PH0: read b_lo,af(cur); stage A+B-h0(nxt); drain B-h1(cur)
#pragma unroll
    for (int n = 0; n < 2; n++) { b_lo[n][0] = ldB(cur, n, 0); b_lo[n][1] = ldB(cur, n, 1); }
#pragma unroll
    for (int jj = 0; jj < 4; jj++) { af[jj][0] = ldA(cur, jj, 0); af[jj][1] = ldA(cur, jj, 1); }
    if (hn) { stageA(nxt, ktn); stageB(nxt, ktn, 0); }
    if (hn) asm volatile("s_waitcnt vmcnt(4)" ::: "memory");
    else    asm volatile("s_waitcnt vmcnt(0)" ::: "memory");
    __builtin_amdgcn_s_barrier();
    __builtin_amdgcn_sched_barrier(0);
    __builtin_amdgcn_s_setprio(1);
#pragma unroll
    for (int jj = 0; jj < 4; jj++)
#pragma unroll
      for (int n = 0; n < 2; n++) {
        acc[jj][n] = mfma16(af[jj][0], b_lo[n][0], acc[jj][n]);
        acc[jj][n] = mfma16(af[jj][1], b_lo[n][1], acc[jj][n]);
      }
    __builtin_amdgcn_s_setprio(0);
    // ---- PH1: read b_hi(cur); stage B-h1(nxt); drain A,B-h0(nxt)
#pragma unroll
    for (int n = 0; n < 2; n++) { b_hi[n][0] = ldB(cur, 2 + n, 0); b_hi[n][1] = ldB(cur, 2 + n, 1); }
    if (hn) stageB(nxt, ktn, 1);
    if (hn) asm volatile("s_waitcnt vmcnt(2)" ::: "memory");
    __builtin_amdgcn_s_barrier();
    __builtin_amdgcn_sched_barrier(0);
    __builtin_amdgcn_s_setprio(1);
#pragma unroll
    for (int jj = 0; jj < 4; jj++)
#pragma unroll
      for (int n = 0; n < 2; n++) {
        acc[jj][2 + n] = mfma16(af[jj][0], b_hi[n][0], acc[jj][2 + n]);
        acc[jj][2 + n] = mfma16(af[jj][1], b_hi[n][1], acc[jj][2 + n]);
      }
    __builtin_amdgcn_s_setprio(0);
  }

#pragma unroll
  for (int jj = 0; jj < 4; jj++)
#pragma unroll
    for (int n = 0; n < 4; n++) {
      const int col = n0 + (4 * n + wn) * 16 + i;
      const float bv = bias[col];
#pragma unroll
      for (int r = 0; r < 4; r++) {
        const int row = m0 + (2 * jj + wm) * 16 + g * 4 + r;
        epilogue_store<EPI>(acc[jj][n][r] + bv, row, col, Nn, res, outf, outb, oq, ok, ov);
      }
    }
}

// ---------------- causal flash attention (paired q-tiles, swapped QK^T) ----------------
// q,k: (BH, T, 128) bf16; vt: (BH, 128, T) bf16; y: (B, T, C) bf16
__global__ __launch_bounds__(256) void attn_kernel(
    const unsigned short* __restrict__ q, const unsigned short* __restrict__ k,
    const unsigned short* __restrict__ vt, unsigned short* __restrict__ y) {
  __shared__ unsigned short Ks[64 * 128];   // swizzled [kv][hs]
  __shared__ unsigned short Vs[128 * 64];   // swizzled [d][kv]
  __shared__ unsigned short Ps[4][16 * 64]; // per-wave swizzled [q=i][kv]
  const int tid = threadIdx.x, lane = tid & 63, w = tid >> 6;
  const int i = lane & 15, g = lane >> 4;
  const int p = blockIdx.x, bh = blockIdx.y;
  const int q0A = p * 64, q0B = (31 - p) * 64;
  const int tB = 31 - p;
  const size_t hb = (size_t)bh * (2048 * 128);
  const float sc2 = 0.08838834764831845f * 1.44269504088896341f;

  bf16x8 qfA[4], qfB[4];
  {
    const int qra = q0A + w * 16 + i, qrb = q0B + w * 16 + i;
#pragma unroll
    for (int kc = 0; kc < 4; kc++) {
      qfA[kc] = *(const bf16x8*)(q + hb + (size_t)qra * 128 + kc * 32 + g * 8);
      qfB[kc] = *(const bf16x8*)(q + hb + (size_t)qrb * 128 + kc * 32 + g * 8);
    }
  }
  f32x4 oA[8] = {}, oB[8] = {};
  float mA = -__builtin_inff(), lA = 0.f, mB = -__builtin_inff(), lB = 0.f;

  auto proc = [&](const bf16x8 (&qf)[4], f32x4 (&oacc)[8], float& mrun, float& lrun,
                  bool diag) {
    f32x4 st[4];
#pragma unroll
    for (int ct = 0; ct < 4; ct++) {
      f32x4 a = {};
      const int kvr = ct * 16 + i;
#pragma unroll
      for (int kc = 0; kc < 4; kc++) {
        bf16x8 kf = *(const bf16x8*)((char*)Ks + kvr * 256 + (((kc * 4 + g) ^ (i & 7)) << 4));
        a = mfma16(kf, qf[kc], a);
      }
      st[ct] = a;
    }
    float tm = -__builtin_inff();
    const int ql = w * 16 + i;
#pragma unroll
    for (int ct = 0; ct < 4; ct++)
#pragma unroll
      for (int r = 0; r < 4; r++) {
        float v = st[ct][r] * sc2;
        if (diag) {
          const int kvl = ct * 16 + g * 4 + r;
          if (kvl > ql) v = -__builtin_inff();
        }
        st[ct][r] = v;
        tm = fmaxf(tm, v);
      }
    tm = fmaxf(tm, __shfl_xor(tm, 16, 64));
    tm = fmaxf(tm, __shfl_xor(tm, 32, 64));
    if (!__all(tm - mrun <= 8.f)) {
      const float mnew = fmaxf(mrun, tm);
      const float al = exp2fast(mrun - mnew);
      float ar[4];
#pragma unroll
      for (int r = 0; r < 4; r++) ar[r] = __shfl(al, g * 4 + r, 64);
#pragma unroll
      for (int dt = 0; dt < 8; dt++)
#pragma unroll
        for (int r = 0; r < 4; r++) oacc[dt][r] *= ar[r];
      lrun *= al;
      mrun = mnew;
    }
    float ps = 0.f;
#pragma unroll
    for (int ct = 0; ct < 4; ct++)
#pragma unroll
      for (int r = 0; r < 4; r++) {
        const float pv = exp2fast(st[ct][r] - mrun);
        st[ct][r] = pv;
        ps += pv;
      }
    ps += __shfl_xor(ps, 16, 64);
    ps += __shfl_xor(ps, 32, 64);
    lrun += ps;
#pragma unroll
    for (int ct = 0; ct < 4; ct++) {
      unsigned w0, w1;
      asm("v_cvt_pk_bf16_f32 %0, %1, %2" : "=v"(w0) : "v"(st[ct][0]), "v"(st[ct][1]));
      asm("v_cvt_pk_bf16_f32 %0, %1, %2" : "=v"(w1) : "v"(st[ct][2]), "v"(st[ct][3]));
      char* pb = (char*)&Ps[w][0] + i * 128 +
                 ((((2 * ct + (g >> 1)) ^ (i & 7)) << 4) + (g & 1) * 8);
      *(uint2*)pb = make_uint2(w0, w1);
    }
    bf16x8 pf[2];
#pragma unroll
    for (int kvc = 0; kvc < 2; kvc++)
      pf[kvc] = *(const bf16x8*)((char*)&Ps[w][0] + i * 128 + (((kvc * 4 + g) ^ (i & 7)) << 4));
#pragma unroll
    for (int dt = 0; dt < 8; dt++) {
      const int dr = dt * 16 + i;
#pragma unroll
      for (int kvc = 0; kvc < 2; kvc++) {
        bf16x8 vf = *(const bf16x8*)((char*)Vs + dr * 128 + (((kvc * 4 + g) ^ (dr & 7)) << 4));
        oacc[dt] = mfma16(pf[kvc], vf, oacc[dt]);
      }
    }
  };

  for (int t = 0; t <= tB; ++t) {
    const int j0 = t * 64;
    __syncthreads();
#pragma unroll
    for (int it = 0; it < 4; it++) {
      const int ci = it * 256 + tid;
      const int kv = ci >> 4, ccl = ci & 15;
      gload_lds16(k + hb + (size_t)(j0 + kv) * 128 + ((ccl ^ (kv & 7)) << 3),
                  (char*)Ks + (size_t)(it * 256 + w * 64) * 16);
      const int dd = ci >> 3, c2l = ci & 7;
      gload_lds16(vt + hb + (size_t)dd * 2048 + j0 + ((c2l ^ (dd & 7)) << 3),
                  (char*)Vs + (size_t)(it * 256 + w * 64) * 16);
    }
    __syncthreads();
    if (t <= p) proc(qfA, oA, mA, lA, t == p);
    proc(qfB, oB, mB, lB, t == tB);
  }

  const int bb = bh >> 4, hh = bh & 15;
  auto finish = [&](const f32x4 (&oacc)[8], float lrun, int q0s) {
    const float inv_i = 1.f / lrun;
    float ir[4];
#pragma unroll
    for (int r = 0; r < 4; r++) ir[r] = __shfl(inv_i, g * 4 + r, 64);
#pragma unroll
    for (int r = 0; r < 4; r++) {
      const int row = q0s + w * 16 + g * 4 + r;
#pragma unroll
      for (int dt = 0; dt < 8; dt++) {
        const int d = dt * 16 + i;
        y[((size_t)(bb * 2048 + row)) * 2048 + hh * 128 + d] = f2bf(oacc[dt][r] * ir[r]);
      }
    }
  };
  finish(oA, lA, q0A);
  finish(oB, lB, q0B);
}

// ---------------- launcher ----------------
extern "C" void kernel_launch(void* const* d_in, const int* in_sizes, int n_in,
                              void* d_out, int out_size, void* d_ws, size_t ws_size,
                              hipStream_t stream) {
  const float* x      = (const float*)d_in[0];
  const float* ln1_w  = (const float*)d_in[1];
  const float* ln1_b  = (const float*)d_in[2];
  const float* w_qkv  = (const float*)d_in[3];
  const float* b_qkv  = (const float*)d_in[4];
  const float* w_proj = (const float*)d_in[5];
  const float* b_proj = (const float*)d_in[6];
  const float* ln2_w  = (const float*)d_in[7];
  const float* ln2_b  = (const float*)d_in[8];
  const float* w_fc   = (const float*)d_in[9];
  const float* b_fc   = (const float*)d_in[10];
  const float* w_fc2  = (const float*)d_in[11];
  const float* b_fc2  = (const float*)d_in[12];

  char* ws = (char*)d_ws;
  unsigned short* wt_qkv  = (unsigned short*)(ws + 0);          // 25165824 B
  unsigned short* wt_proj = (unsigned short*)(ws + 25165824);   // 8388608
  unsigned short* qb      = (unsigned short*)(ws + 33554432);   // 16777216
  unsigned short* kb      = (unsigned short*)(ws + 50331648);   // 16777216
  unsigned short* wt_fc   = (unsigned short*)(ws + 67108864);   // 33554432
  unsigned short* wt_fc2  = (unsigned short*)(ws + 100663296);  // 33554432
  unsigned short* hb      = (unsigned short*)(ws + 134217728);  // 16777216 (h1/h2)
  unsigned short* vtb     = (unsigned short*)(ws + 150994944);  // 16777216
  unsigned short* yb      = (unsigned short*)(ws + 167772160);  // 16777216 (vb then y)
  float*          x1      = (float*)(ws + 184549376);           // 33554432 (ends 218103808)
  unsigned short* hfc     = (unsigned short*)(ws + 0);          // 67108864, aliases dead wt_qkv/wt_proj/qb/kb
  float* outp = (float*)d_out;

  dim3 tb(32, 8);
  transpose_to_bf16<<<dim3(6144 / 32, 2048 / 32), tb, 0, stream>>>(w_qkv, wt_qkv, 2048, 6144);
  transpose_to_bf16<<<dim3(2048 / 32, 2048 / 32), tb, 0, stream>>>(w_proj, wt_proj, 2048, 2048);
  transpose_to_bf16<<<dim3(8192 / 32, 2048 / 32), tb, 0, stream>>>(w_fc, wt_fc, 2048, 8192);
  transpose_to_bf16<<<dim3(2048 / 32, 8192 / 32), tb, 0, stream>>>(w_fc2, wt_fc2, 8192, 2048);

  ln_kernel<<<4096, 256, 0, stream>>>(x, ln1_w, ln1_b, hb);

  // qkv: 128x256 tiles -> 32x24 = 768 blocks (3 clean rounds)
  gemm128<0><<<768, 512, 0, stream>>>(
      hb, wt_qkv, b_qkv, nullptr, nullptr, nullptr, qb, kb, yb, 6144, 2048, 24);
  transpose_v<<<dim3(2048 / 32, 128 / 32, 32), tb, 0, stream>>>(yb, vtb);

  // paired causal q-tiles: 16 pairs x 32 bh = 512 blocks, uniform work
  attn_kernel<<<dim3(16, 32), 256, 0, stream>>>(qb, kb, vtb, yb);

  // proj + residual -> x1 (f32): 32x8 = 256 blocks (1 clean round)
  gemm128<2><<<256, 512, 0, stream>>>(
      yb, wt_proj, b_proj, x, x1, nullptr, nullptr, nullptr, nullptr, 2048, 2048, 8);

  ln_kernel<<<4096, 256, 0, stream>>>(x1, ln2_w, ln2_b, hb);

  // fc + GELU -> hfc (bf16): 256x256 tiles, 512 blocks (2 clean rounds)
  gemm256<1><<<512, 512, 0, stream>>>(
      hb, wt_fc, b_fc, nullptr, nullptr, hfc, nullptr, nullptr, nullptr, 8192, 2048, 32);

  // fc2 + residual -> out (f32): 32x8 = 256 blocks (1 clean round)
  gemm128<2><<<256, 512, 0, stream>>>(
      hfc, wt_fc2, b_fc2, x1, outp, nullptr, nullptr, nullptr, nullptr, 2048, 8192, 8);
}